// Round 14
// baseline (386.034 us; speedup 1.0000x reference)
//
#include <hip/hip_runtime.h>
#include <hip/hip_bf16.h>
#include <cstdint>
#include <cstddef>

#define S_LEN 2048
#define DM 1024
#define NEGV -1.0e9f

typedef __attribute__((ext_vector_type(8))) short bf16x8;
typedef __attribute__((ext_vector_type(4))) float f32x4;
typedef __attribute__((ext_vector_type(4))) unsigned short us4;
typedef __attribute__((ext_vector_type(4))) int i32x4;
typedef __attribute__((ext_vector_type(4))) unsigned int ui32x4;
typedef __attribute__((ext_vector_type(2))) unsigned int u32x2;

__device__ __forceinline__ unsigned short f2bf(float f) {
  unsigned int u = __float_as_uint(f);
  unsigned int r = (u + 0x7fffu + ((u >> 16) & 1u)) >> 16;
  return (unsigned short)r;
}

__device__ __forceinline__ unsigned int pack_bf2(float a, float b) {
  return (unsigned int)f2bf(a) | ((unsigned int)f2bf(b) << 16);
}

__device__ __forceinline__ void async_copy16(const void* g, void* l) {
  __builtin_amdgcn_global_load_lds((const __attribute__((address_space(1))) void*)g,
                                   (__attribute__((address_space(3))) void*)l, 16, 0, 0);
}

// ---------------- f32 -> bf16 convert ----------------
__global__ void cvt_kernel(const float* __restrict__ src, unsigned short* __restrict__ dst, int n4) {
  int i = blockIdx.x * blockDim.x + threadIdx.x;
  if (i >= n4) return;
  const float4 v = reinterpret_cast<const float4*>(src)[i];
  us4 o;
  o[0] = f2bf(v.x); o[1] = f2bf(v.y); o[2] = f2bf(v.z); o[3] = f2bf(v.w);
  reinterpret_cast<us4*>(dst)[i] = o;
}

// ---------------- mask int32 -> bitmask (33.5 MB -> 1 MB) ----------------
__global__ __launch_bounds__(256) void maskbits_kernel(const int* __restrict__ mask,
                                                       unsigned int* __restrict__ mb) {
  const int idx = blockIdx.x * 256 + threadIdx.x;   // 262144 total
  const int row = idx >> 6, w = idx & 63;
  const int* src = mask + (size_t)row * S_LEN + w * 32;
  unsigned int r = 0;
#pragma unroll
  for (int j = 0; j < 8; ++j) {
    const i32x4 v = *(const i32x4*)(src + j * 4);
    r |= (v[0] ? 1u : 0u) << (j * 4 + 0);
    r |= (v[1] ? 1u : 0u) << (j * 4 + 1);
    r |= (v[2] ? 1u : 0u) << (j * 4 + 2);
    r |= (v[3] ? 1u : 0u) << (j * 4 + 3);
  }
  mb[(size_t)row * 64 + w] = r;
}

// ---------------- projection GEMM (unchanged, passed) ----------------
__global__ __launch_bounds__(256) void proj_gemm(
    const unsigned short* __restrict__ Xq, const unsigned short* __restrict__ Wqw,
    const float* __restrict__ bq, unsigned short* __restrict__ Cq,
    const unsigned short* __restrict__ Xk, const unsigned short* __restrict__ Wkw,
    const float* __restrict__ bk, unsigned short* __restrict__ Ck,
    const unsigned short* __restrict__ Xv, const unsigned short* __restrict__ Wvw,
    const float* __restrict__ bv, unsigned short* __restrict__ Cv) {
  const unsigned short* X; const unsigned short* W; const float* bias; unsigned short* C;
  if (blockIdx.z == 0)      { X = Xq; W = Wqw; bias = bq; C = Cq; }
  else if (blockIdx.z == 1) { X = Xk; W = Wkw; bias = bk; C = Ck; }
  else                      { X = Xv; W = Wvw; bias = bv; C = Cv; }

  __shared__ unsigned short Ab[128 * 64];
  __shared__ unsigned short Bb[128 * 64];

  const int t  = threadIdx.x;
  const int wv = t >> 6, l = t & 63;
  const int lr = l & 15, lg = l >> 4;
  const int wr = wv >> 1, wc = wv & 1;
  const int m0 = blockIdx.y * 128, n0 = blockIdx.x * 128;

  const f32x4 fz = {0.f, 0.f, 0.f, 0.f};
  f32x4 acc[4][4];
#pragma unroll
  for (int m = 0; m < 4; ++m)
#pragma unroll
    for (int n = 0; n < 4; ++n) acc[m][n] = fz;

  const int srow = t >> 3;
  const int sc16 = t & 7;

  for (int kt = 0; kt < 16; ++kt) {
    const int kb = kt * 64;
#pragma unroll
    for (int it = 0; it < 4; ++it) {
      const int row = it * 32 + srow;
      const int c16 = sc16 ^ (row & 7);
      const unsigned short* gA = X + (size_t)(m0 + row) * DM + kb + c16 * 8;
      const unsigned short* gB = W + (size_t)(n0 + row) * DM + kb + c16 * 8;
      async_copy16(gA, (char*)Ab + it * 4096 + wv * 1024);
      async_copy16(gB, (char*)Bb + it * 4096 + wv * 1024);
    }
    __syncthreads();
#pragma unroll
    for (int kk = 0; kk < 2; ++kk) {
      bf16x8 af[4], bfr[4];
      const int c16 = kk * 4 + lg;
      const int sw = (c16 ^ (lr & 7)) * 16;
#pragma unroll
      for (int m = 0; m < 4; ++m) {
        const int row = wr * 64 + m * 16 + lr;
        af[m] = *(const bf16x8*)((const char*)Ab + row * 128 + sw);
      }
#pragma unroll
      for (int n = 0; n < 4; ++n) {
        const int row = wc * 64 + n * 16 + lr;
        bfr[n] = *(const bf16x8*)((const char*)Bb + row * 128 + sw);
      }
#pragma unroll
      for (int m = 0; m < 4; ++m)
#pragma unroll
        for (int n = 0; n < 4; ++n)
          acc[m][n] = __builtin_amdgcn_mfma_f32_16x16x32_bf16(af[m], bfr[n], acc[m][n], 0, 0, 0);
    }
    __syncthreads();
  }

#pragma unroll
  for (int n = 0; n < 4; ++n) {
    const int ccol = n0 + wc * 64 + n * 16 + lr;
    const float bb = bias[ccol];
#pragma unroll
    for (int m = 0; m < 4; ++m) {
      const int crow0 = m0 + wr * 64 + m * 16 + lg * 4;
#pragma unroll
      for (int j = 0; j < 4; ++j)
        C[(size_t)(crow0 + j) * DM + ccol] = f2bf(acc[m][n][j] + bb);
    }
  }
}

// ---------------- V transpose: [4096,1024] -> [1024,4096] ----------------
__global__ void transpose_bf(const unsigned short* __restrict__ src, unsigned short* __restrict__ dst) {
  __shared__ unsigned short tb[32][33];
  const int x = threadIdx.x & 31, y = threadIdx.x >> 5;
  const int bx = blockIdx.x, by = blockIdx.y;
#pragma unroll
  for (int r = 0; r < 32; r += 8)
    tb[r + y][x] = src[(size_t)(by * 32 + r + y) * DM + bx * 32 + x];
  __syncthreads();
#pragma unroll
  for (int r = 0; r < 32; r += 8)
    dst[(size_t)(bx * 32 + r + y) * 4096 + by * 32 + x] = tb[x][r + y];
}

// ---------------- fused attention v13: fill-shaped contiguous attn stores ----------------
// vs v9: attn stores moved to a post-PV phase of 4 block-cooperative rounds.
// Round r: waves re-stage rows 4r..4r+3 x all 2048 keys of packed P into a
// block-wide LDS buffer; each wave then streams ONE contiguous 1024-f32 row
// segment (4 x 1KB store instrs — the exact shape the 6.7 TB/s fill kernel uses).
// Old shape was 4 rows x 256B with 8KB row stride per instr (~1.8 TB/s effective).
__global__ __launch_bounds__(512, 4) void attn13_kernel(
    const unsigned short* __restrict__ Qp, const unsigned short* __restrict__ Kp,
    const unsigned short* __restrict__ Vt, const unsigned int* __restrict__ mbits,
    float* __restrict__ outp, float* __restrict__ attnp) {
  __shared__ float rsred[8][16];    // 512 B
  __shared__ float rinv16[16];      // 64 B
  __shared__ char uni[8][4224];     // 33 KB: per-wave P bufs U store-staging U outred

  const int bx = blockIdx.x;
  const int c  = bx & 7;            // XCD (round-robin dispatch)
  const int s  = bx >> 3;           // temporal order within XCD
  const int j  = s & 3;             // which of this XCD's 4 (b,h) pairs
  const int qt = s >> 2;            // 0..127, outer
  const int bh = c * 4 + j;
  const int b  = bh >> 4, h = bh & 15;
  const int q0 = qt << 4;

  const int w = threadIdx.x >> 6, l = threadIdx.x & 63;
  const int lr = l & 15, lg = l >> 4;
  const int kw0 = w << 8;           // 256 keys per wave

  const float scale = 0.125f;
  const f32x4 fz = {0.f, 0.f, 0.f, 0.f};

  // Q as B-operand: lane holds Q[q0+lr][lg*8..+7]
  const unsigned short* Qh = Qp + (size_t)(b * S_LEN + q0 + lr) * DM + h * 64;
  const bf16x8 qf0 = *(const bf16x8*)(Qh + lg * 8);
  const bf16x8 qf1 = *(const bf16x8*)(Qh + 32 + lg * 8);

  const unsigned short* Kh = Kp + (size_t)b * S_LEN * DM + h * 64 + (size_t)kw0 * DM;

  // bitmask slice: 8 u32 loaded once (1 MB total, L2/L3-resident)
  const unsigned int* mbr = mbits + ((size_t)(b * S_LEN + q0 + lr) << 6) + (kw0 >> 5);
  const ui32x4 mwa = *(const ui32x4*)(mbr);
  const ui32x4 mwb = *(const ui32x4*)(mbr + 4);

  // ---- pass 1: QK^T + bit-mask + exp, packed bf16 in regs ----
  unsigned int pkA[16], pkB[16];
  float rs = 0.f;
#pragma unroll
  for (int i = 0; i < 16; ++i) {
    const unsigned short* Kr = Kh + (size_t)(i * 16 + lr) * DM;
    const bf16x8 ka0 = *(const bf16x8*)(Kr + lg * 8);
    const bf16x8 ka1 = *(const bf16x8*)(Kr + 32 + lg * 8);
    f32x4 sc = fz;
    sc = __builtin_amdgcn_mfma_f32_16x16x32_bf16(ka0, qf0, sc, 0, 0, 0);
    sc = __builtin_amdgcn_mfma_f32_16x16x32_bf16(ka1, qf1, sc, 0, 0, 0);
    const unsigned int wsel = (i < 8) ? mwa[i >> 1] : mwb[(i - 8) >> 1];
    const unsigned int nib = (wsel >> ((i & 1) * 16 + lg * 4)) & 15u;
    const float e0 = __expf((nib & 1u) ? sc[0] * scale : NEGV);
    const float e1 = __expf((nib & 2u) ? sc[1] * scale : NEGV);
    const float e2 = __expf((nib & 4u) ? sc[2] * scale : NEGV);
    const float e3 = __expf((nib & 8u) ? sc[3] * scale : NEGV);
    rs += (e0 + e1) + (e2 + e3);
    pkA[i] = pack_bf2(e0, e1);
    pkB[i] = pack_bf2(e2, e3);
  }
  rs += __shfl_xor(rs, 16, 64);
  rs += __shfl_xor(rs, 32, 64);
  if (l < 16) rsred[w][l] = rs;
  __syncthreads();
  if (threadIdx.x < 16) {
    float s0 = 0.f;
#pragma unroll
    for (int ww = 0; ww < 8; ++ww) s0 += rsred[ww][threadIdx.x];
    rinv16[threadIdx.x] = 1.0f / s0;
  }
  __syncthreads();

  // ---- PV loop: loads + MFMA only (no global stores in flight) ----
  const unsigned short* Vh = Vt + (size_t)(h * 64) * (2 * S_LEN) + (size_t)b * S_LEN + kw0;
  unsigned short* pbase = (unsigned short*)uni[w];

  f32x4 oacc[4];
#pragma unroll
  for (int n = 0; n < 4; ++n) oacc[n] = fz;

#pragma unroll
  for (int pr = 0; pr < 4; ++pr) {
    const int kb = pr * 64;
    unsigned short* pb = pbase + (pr & 1) * 1056;  // 16 rows x 66 sh, double-buffered

    bf16x8 vbr[2][4];
#pragma unroll
    for (int s2 = 0; s2 < 2; ++s2)
#pragma unroll
      for (int n = 0; n < 4; ++n)
        vbr[s2][n] = *(const bf16x8*)(Vh + (size_t)(n * 16 + lr) * (2 * S_LEN) + kb + s2 * 32 + lg * 8);

#pragma unroll
    for (int s2 = 0; s2 < 2; ++s2) {
      const int wi = pr * 2 + s2;
      const u32x2 wv0 = {pkA[2 * wi],     pkB[2 * wi]};
      const u32x2 wv1 = {pkA[2 * wi + 1], pkB[2 * wi + 1]};
      *(u32x2*)(pb + lr * 66 + s2 * 32 + lg * 4) = wv0;
      *(u32x2*)(pb + lr * 66 + s2 * 32 + 16 + lg * 4) = wv1;
    }
#pragma unroll
    for (int s2 = 0; s2 < 2; ++s2) {
      const bf16x8 pa = *(const bf16x8*)(pb + lr * 66 + s2 * 32 + lg * 8);
#pragma unroll
      for (int n = 0; n < 4; ++n)
        oacc[n] = __builtin_amdgcn_mfma_f32_16x16x32_bf16(pa, vbr[s2][n], oacc[n], 0, 0, 0);
    }
  }

  asm volatile("s_waitcnt lgkmcnt(0)" ::: "memory");
  __syncthreads();  // all waves done with per-wave P buffers; uni becomes block staging

  // ---- store phase: 4 rounds, each = 4 q-rows x 2048 keys, contiguous 1KB bursts ----
  unsigned short* sb = (unsigned short*)uni;   // block-wide staging: 4 rows x 2056 sh = 16.4 KB
  const int row4 = w >> 1;                     // this wave's row within the round's 4
  const int half = w & 1;                      // left/right 1024 keys
  float* attnBase = attnp + (size_t)((b * 16 + h) * S_LEN + q0) * S_LEN;

#pragma unroll
  for (int r = 0; r < 4; ++r) {
    // stage: lanes whose q-row (lr) is in this round write their packed P slice
    if ((lr >> 2) == r) {
      unsigned short* dst = sb + (lr & 3) * 2056 + kw0;
#pragma unroll
      for (int i = 0; i < 16; ++i) {
        const u32x2 wv = {pkA[i], pkB[i]};
        *(u32x2*)(dst + i * 16 + lg * 4) = wv;
      }
    }
    __syncthreads();
    // stream: wave w stores row (4r+row4), columns [half*1024, half*1024+1024)
    {
      const int grow = r * 4 + row4;
      const float rv = rinv16[grow];
      float* orow = attnBase + (size_t)grow * S_LEN + half * 1024;
      const unsigned short* srow = sb + row4 * 2056 + half * 1024;
#pragma unroll
      for (int it = 0; it < 4; ++it) {
        const us4 p4 = *(const us4*)(srow + it * 256 + l * 4);
        const f32x4 st = {__uint_as_float((unsigned)p4[0] << 16) * rv,
                          __uint_as_float((unsigned)p4[1] << 16) * rv,
                          __uint_as_float((unsigned)p4[2] << 16) * rv,
                          __uint_as_float((unsigned)p4[3] << 16) * rv};
        *(f32x4*)(orow + it * 256 + l * 4) = st;   // 64 lanes x 16B = 1KB contiguous
      }
    }
    __syncthreads();
  }

  // ---- cross-wave out reduction (uni reused again) ----
  float* outred = (float*)uni[w];
#pragma unroll
  for (int n = 0; n < 4; ++n)
#pragma unroll
    for (int jj = 0; jj < 4; ++jj)
      outred[(lg * 4 + jj) * 64 + n * 16 + lr] = oacc[n][jj];
  __syncthreads();
  if (threadIdx.x < 256) {
    const int q = threadIdx.x >> 4;
    const int d0 = (threadIdx.x & 15) * 4;
    const float rq = rinv16[q];
    float4 o = {0.f, 0.f, 0.f, 0.f};
#pragma unroll
    for (int ww = 0; ww < 8; ++ww) {
      const f32x4 sv = *(const f32x4*)((const float*)uni[ww] + q * 64 + d0);
      o.x += sv[0]; o.y += sv[1]; o.z += sv[2]; o.w += sv[3];
    }
    o.x *= rq; o.y *= rq; o.z *= rq; o.w *= rq;
    *(float4*)(outp + (size_t)(b * S_LEN + q0 + q) * DM + h * 64 + d0) = o;
  }
}

extern "C" void kernel_launch(void* const* d_in, const int* in_sizes, int n_in,
                              void* d_out, int out_size, void* d_ws, size_t ws_size,
                              hipStream_t stream) {
  const float* query = (const float*)d_in[0];
  const float* key_  = (const float*)d_in[1];
  const float* value = (const float*)d_in[2];
  const int*   mask  = (const int*)d_in[3];
  const float* Wq = (const float*)d_in[4];
  const float* bq = (const float*)d_in[5];
  const float* Wk = (const float*)d_in[6];
  const float* bk = (const float*)d_in[7];
  const float* Wv = (const float*)d_in[8];
  const float* bv = (const float*)d_in[9];

  float* outp  = (float*)d_out;
  float* attnp = outp + (size_t)2 * S_LEN * DM;

  unsigned short* ws  = (unsigned short*)d_ws;
  unsigned short* qbf = ws;
  unsigned short* kbf = qbf + 4194304;
  unsigned short* vbf = kbf + 4194304;
  unsigned short* wqb = vbf + 4194304;
  unsigned short* wkb = wqb + 1048576;
  unsigned short* wvb = wkb + 1048576;
  unsigned short* qp  = wvb + 1048576;
  unsigned short* kp  = qp + 4194304;
  unsigned short* vp  = kp + 4194304;
  unsigned short* vt  = vp + 4194304;
  unsigned int*   mb  = (unsigned int*)(vt + 4194304);   // 1 MB bitmask

  cvt_kernel<<<4096, 256, 0, stream>>>(query, qbf, 1048576);
  cvt_kernel<<<4096, 256, 0, stream>>>(key_,  kbf, 1048576);
  cvt_kernel<<<4096, 256, 0, stream>>>(value, vbf, 1048576);
  cvt_kernel<<<1024, 256, 0, stream>>>(Wq, wqb, 262144);
  cvt_kernel<<<1024, 256, 0, stream>>>(Wk, wkb, 262144);
  cvt_kernel<<<1024, 256, 0, stream>>>(Wv, wvb, 262144);
  maskbits_kernel<<<1024, 256, 0, stream>>>(mask, mb);

  proj_gemm<<<dim3(8, 32, 3), 256, 0, stream>>>(qbf, wqb, bq, qp,
                                                kbf, wkb, bk, kp,
                                                vbf, wvb, bv, vp);
  transpose_bf<<<dim3(32, 128), 256, 0, stream>>>(vp, vt);
  attn13_kernel<<<4096, 512, 0, stream>>>(qp, kp, vt, mb, outp, attnp);
}

// Round 15
// 256.394 us; speedup vs baseline: 1.5056x; 1.5056x over previous
//
#include <hip/hip_runtime.h>
#include <hip/hip_bf16.h>
#include <cstdint>
#include <cstddef>

#define S_LEN 2048
#define DM 1024
#define NEGV -1.0e9f

typedef __attribute__((ext_vector_type(8))) short bf16x8;
typedef __attribute__((ext_vector_type(4))) float f32x4;
typedef __attribute__((ext_vector_type(4))) unsigned short us4;
typedef __attribute__((ext_vector_type(4))) int i32x4;
typedef __attribute__((ext_vector_type(4))) unsigned int ui32x4;
typedef __attribute__((ext_vector_type(2))) unsigned int u32x2;

__device__ __forceinline__ unsigned short f2bf(float f) {
  unsigned int u = __float_as_uint(f);
  unsigned int r = (u + 0x7fffu + ((u >> 16) & 1u)) >> 16;
  return (unsigned short)r;
}

__device__ __forceinline__ unsigned int pack_bf2(float a, float b) {
  return (unsigned int)f2bf(a) | ((unsigned int)f2bf(b) << 16);
}

__device__ __forceinline__ void async_copy16(const void* g, void* l) {
  __builtin_amdgcn_global_load_lds((const __attribute__((address_space(1))) void*)g,
                                   (__attribute__((address_space(3))) void*)l, 16, 0, 0);
}

// ---------------- f32 -> bf16 convert ----------------
__global__ void cvt_kernel(const float* __restrict__ src, unsigned short* __restrict__ dst, int n4) {
  int i = blockIdx.x * blockDim.x + threadIdx.x;
  if (i >= n4) return;
  const float4 v = reinterpret_cast<const float4*>(src)[i];
  us4 o;
  o[0] = f2bf(v.x); o[1] = f2bf(v.y); o[2] = f2bf(v.z); o[3] = f2bf(v.w);
  reinterpret_cast<us4*>(dst)[i] = o;
}

// ---------------- mask int32 -> bitmask (33.5 MB -> 1 MB) ----------------
__global__ __launch_bounds__(256) void maskbits_kernel(const int* __restrict__ mask,
                                                       unsigned int* __restrict__ mb) {
  const int idx = blockIdx.x * 256 + threadIdx.x;   // 262144 total
  const int row = idx >> 6, w = idx & 63;
  const int* src = mask + (size_t)row * S_LEN + w * 32;
  unsigned int r = 0;
#pragma unroll
  for (int j = 0; j < 8; ++j) {
    const i32x4 v = *(const i32x4*)(src + j * 4);
    r |= (v[0] ? 1u : 0u) << (j * 4 + 0);
    r |= (v[1] ? 1u : 0u) << (j * 4 + 1);
    r |= (v[2] ? 1u : 0u) << (j * 4 + 2);
    r |= (v[3] ? 1u : 0u) << (j * 4 + 3);
  }
  mb[(size_t)row * 64 + w] = r;
}

// ---------------- projection GEMM (unchanged, passed) ----------------
__global__ __launch_bounds__(256) void proj_gemm(
    const unsigned short* __restrict__ Xq, const unsigned short* __restrict__ Wqw,
    const float* __restrict__ bq, unsigned short* __restrict__ Cq,
    const unsigned short* __restrict__ Xk, const unsigned short* __restrict__ Wkw,
    const float* __restrict__ bk, unsigned short* __restrict__ Ck,
    const unsigned short* __restrict__ Xv, const unsigned short* __restrict__ Wvw,
    const float* __restrict__ bv, unsigned short* __restrict__ Cv) {
  const unsigned short* X; const unsigned short* W; const float* bias; unsigned short* C;
  if (blockIdx.z == 0)      { X = Xq; W = Wqw; bias = bq; C = Cq; }
  else if (blockIdx.z == 1) { X = Xk; W = Wkw; bias = bk; C = Ck; }
  else                      { X = Xv; W = Wvw; bias = bv; C = Cv; }

  __shared__ unsigned short Ab[128 * 64];
  __shared__ unsigned short Bb[128 * 64];

  const int t  = threadIdx.x;
  const int wv = t >> 6, l = t & 63;
  const int lr = l & 15, lg = l >> 4;
  const int wr = wv >> 1, wc = wv & 1;
  const int m0 = blockIdx.y * 128, n0 = blockIdx.x * 128;

  const f32x4 fz = {0.f, 0.f, 0.f, 0.f};
  f32x4 acc[4][4];
#pragma unroll
  for (int m = 0; m < 4; ++m)
#pragma unroll
    for (int n = 0; n < 4; ++n) acc[m][n] = fz;

  const int srow = t >> 3;
  const int sc16 = t & 7;

  for (int kt = 0; kt < 16; ++kt) {
    const int kb = kt * 64;
#pragma unroll
    for (int it = 0; it < 4; ++it) {
      const int row = it * 32 + srow;
      const int c16 = sc16 ^ (row & 7);
      const unsigned short* gA = X + (size_t)(m0 + row) * DM + kb + c16 * 8;
      const unsigned short* gB = W + (size_t)(n0 + row) * DM + kb + c16 * 8;
      async_copy16(gA, (char*)Ab + it * 4096 + wv * 1024);
      async_copy16(gB, (char*)Bb + it * 4096 + wv * 1024);
    }
    __syncthreads();
#pragma unroll
    for (int kk = 0; kk < 2; ++kk) {
      bf16x8 af[4], bfr[4];
      const int c16 = kk * 4 + lg;
      const int sw = (c16 ^ (lr & 7)) * 16;
#pragma unroll
      for (int m = 0; m < 4; ++m) {
        const int row = wr * 64 + m * 16 + lr;
        af[m] = *(const bf16x8*)((const char*)Ab + row * 128 + sw);
      }
#pragma unroll
      for (int n = 0; n < 4; ++n) {
        const int row = wc * 64 + n * 16 + lr;
        bfr[n] = *(const bf16x8*)((const char*)Bb + row * 128 + sw);
      }
#pragma unroll
      for (int m = 0; m < 4; ++m)
#pragma unroll
        for (int n = 0; n < 4; ++n)
          acc[m][n] = __builtin_amdgcn_mfma_f32_16x16x32_bf16(af[m], bfr[n], acc[m][n], 0, 0, 0);
    }
    __syncthreads();
  }

#pragma unroll
  for (int n = 0; n < 4; ++n) {
    const int ccol = n0 + wc * 64 + n * 16 + lr;
    const float bb = bias[ccol];
#pragma unroll
    for (int m = 0; m < 4; ++m) {
      const int crow0 = m0 + wr * 64 + m * 16 + lg * 4;
#pragma unroll
      for (int j = 0; j < 4; ++j)
        C[(size_t)(crow0 + j) * DM + ccol] = f2bf(acc[m][n][j] + bb);
    }
  }
}

// ---------------- V transpose: [4096,1024] -> [1024,4096] ----------------
__global__ void transpose_bf(const unsigned short* __restrict__ src, unsigned short* __restrict__ dst) {
  __shared__ unsigned short tb[32][33];
  const int x = threadIdx.x & 31, y = threadIdx.x >> 5;
  const int bx = blockIdx.x, by = blockIdx.y;
#pragma unroll
  for (int r = 0; r < 32; r += 8)
    tb[r + y][x] = src[(size_t)(by * 32 + r + y) * DM + bx * 32 + x];
  __syncthreads();
#pragma unroll
  for (int r = 0; r < 32; r += 8)
    dst[(size_t)(bx * 32 + r + y) * 4096 + by * 32 + x] = tb[x][r + y];
}

// ---------------- K repack into MFMA-fragment order ----------------
// Kpack[((b*16+h)*128 + kb)*1024 + chunk*512 + lane*8 + e] =
//   Kp[(b*2048 + kb*16 + (lane&15))*1024 + h*64 + chunk*32 + (lane>>4)*8 + e]
// -> pass-1 load = base + lane*16B: one contiguous 1KB burst per instruction.
__global__ __launch_bounds__(256) void kpack_kernel(const unsigned short* __restrict__ Kp,
                                                    unsigned short* __restrict__ Kpack) {
  const int tid = blockIdx.x * 256 + threadIdx.x;   // 524288 total
  const int lane = tid & 63;
  const int chunk = (tid >> 6) & 1;
  const int kb = (tid >> 7) & 127;
  const int h = (tid >> 14) & 15;
  const int b = tid >> 18;
  const unsigned short* src = Kp + (size_t)(b * 2048 + kb * 16 + (lane & 15)) * 1024
                                 + h * 64 + chunk * 32 + (lane >> 4) * 8;
  unsigned short* dst = Kpack + ((size_t)((b * 16 + h) * 128 + kb) * 2 + chunk) * 512 + lane * 8;
  *(bf16x8*)dst = *(const bf16x8*)src;
}

// ---------------- V repack into MFMA-fragment order (from Vt) ----------------
// Vpack[((b*16+h)*256 + blk)*512 + lane*8 + e], blk = ((w*4+pr)*2+s2)*4+n =
//   Vt[(h*64 + n*16 + (lane&15))*4096 + b*2048 + w*256 + pr*64 + s2*32 + (lane>>4)*8 + e]
__global__ __launch_bounds__(256) void vpack_kernel(const unsigned short* __restrict__ Vt,
                                                    unsigned short* __restrict__ Vpack) {
  const int tid = blockIdx.x * 256 + threadIdx.x;   // 524288 total
  const int lane = tid & 63;
  const int n  = (tid >> 6) & 3;
  const int s2 = (tid >> 8) & 1;
  const int pr = (tid >> 9) & 3;
  const int w  = (tid >> 11) & 7;
  const int h  = (tid >> 14) & 15;
  const int b  = tid >> 18;
  const unsigned short* src = Vt + (size_t)(h * 64 + n * 16 + (lane & 15)) * 4096
                                 + b * 2048 + w * 256 + pr * 64 + s2 * 32 + (lane >> 4) * 8;
  const int blk = ((w * 4 + pr) * 2 + s2) * 4 + n;
  unsigned short* dst = Vpack + ((size_t)(b * 16 + h) * 256 + blk) * 512 + lane * 8;
  *(bf16x8*)dst = *(const bf16x8*)src;
}

// ---------------- fused attention v15: packed K/V -> all inner loads contiguous 1KB ----------------
// vs v9: K and V consumed from fragment-order packed buffers; every inner-loop load
// is base + lane*16B (8 full 128B lines per instruction) instead of a 16-row x 64B
// gather (16 sub-line segments). Store path, bitmask, supertile identical to v9.
__global__ __launch_bounds__(512, 4) void attn15_kernel(
    const unsigned short* __restrict__ Qp, const unsigned short* __restrict__ Kpk,
    const unsigned short* __restrict__ Vpk, const unsigned int* __restrict__ mbits,
    float* __restrict__ outp, float* __restrict__ attnp) {
  __shared__ float rsred[8][16];    // 512 B
  __shared__ float rinv16[16];      // 64 B
  __shared__ char uni[8][4224];     // 33 KB: per-wave 2x(16x66 sh) P buffers U outred

  const int bx = blockIdx.x;
  const int c  = bx & 7;            // XCD (round-robin dispatch)
  const int s  = bx >> 3;           // temporal order within XCD
  const int j  = s & 3;             // which of this XCD's 4 (b,h) pairs
  const int qt = s >> 2;            // 0..127, outer
  const int bh = c * 4 + j;
  const int b  = bh >> 4, h = bh & 15;
  const int q0 = qt << 4;

  const int w = threadIdx.x >> 6, l = threadIdx.x & 63;
  const int lr = l & 15, lg = l >> 4;
  const int kw0 = w << 8;           // 256 keys per wave

  const float scale = 0.125f;
  const f32x4 fz = {0.f, 0.f, 0.f, 0.f};

  // Q as B-operand: lane holds Q[q0+lr][lg*8..+7]
  const unsigned short* Qh = Qp + (size_t)(b * S_LEN + q0 + lr) * DM + h * 64;
  const bf16x8 qf0 = *(const bf16x8*)(Qh + lg * 8);
  const bf16x8 qf1 = *(const bf16x8*)(Qh + 32 + lg * 8);

  // packed K base for this wave: 16 kb-blocks of 1024 shorts
  const unsigned short* Kw = Kpk + (size_t)((b * 16 + h) * 128 + w * 16) * 1024;

  // bitmask slice: 8 u32 loaded once (1 MB total, L2/L3-resident)
  const unsigned int* mbr = mbits + ((size_t)(b * S_LEN + q0 + lr) << 6) + (kw0 >> 5);
  const ui32x4 mwa = *(const ui32x4*)(mbr);
  const ui32x4 mwb = *(const ui32x4*)(mbr + 4);

  // ---- pass 1: QK^T + bit-mask + exp, packed bf16 in regs ----
  unsigned int pkA[16], pkB[16];
  float rs = 0.f;
#pragma unroll
  for (int i = 0; i < 16; ++i) {
    const bf16x8 ka0 = *(const bf16x8*)(Kw + i * 1024 + l * 8);
    const bf16x8 ka1 = *(const bf16x8*)(Kw + i * 1024 + 512 + l * 8);
    f32x4 sc = fz;
    sc = __builtin_amdgcn_mfma_f32_16x16x32_bf16(ka0, qf0, sc, 0, 0, 0);
    sc = __builtin_amdgcn_mfma_f32_16x16x32_bf16(ka1, qf1, sc, 0, 0, 0);
    const unsigned int wsel = (i < 8) ? mwa[i >> 1] : mwb[(i - 8) >> 1];
    const unsigned int nib = (wsel >> ((i & 1) * 16 + lg * 4)) & 15u;
    const float e0 = __expf((nib & 1u) ? sc[0] * scale : NEGV);
    const float e1 = __expf((nib & 2u) ? sc[1] * scale : NEGV);
    const float e2 = __expf((nib & 4u) ? sc[2] * scale : NEGV);
    const float e3 = __expf((nib & 8u) ? sc[3] * scale : NEGV);
    rs += (e0 + e1) + (e2 + e3);
    pkA[i] = pack_bf2(e0, e1);
    pkB[i] = pack_bf2(e2, e3);
  }
  rs += __shfl_xor(rs, 16, 64);
  rs += __shfl_xor(rs, 32, 64);
  if (l < 16) rsred[w][l] = rs;
  __syncthreads();
  if (threadIdx.x < 16) {
    float s0 = 0.f;
#pragma unroll
    for (int ww = 0; ww < 8; ++ww) s0 += rsred[ww][threadIdx.x];
    rinv16[threadIdx.x] = 1.0f / s0;
  }
  __syncthreads();

  float rv4[4];
#pragma unroll
  for (int i = 0; i < 4; ++i) rv4[i] = rinv16[(l >> 4) + 4 * i];

  // ---- per-64-key pair: packed V loads first, staged P, NT stores, PV ----
  float* attnB = attnp + (size_t)((b * 16 + h) * S_LEN + q0) * S_LEN + kw0;
  const unsigned short* Vw = Vpk + ((size_t)(b * 16 + h) * 256 + w * 32) * 512;
  unsigned short* pbase = (unsigned short*)uni[w];

  f32x4 oacc[4];
#pragma unroll
  for (int n = 0; n < 4; ++n) oacc[n] = fz;

#pragma unroll
  for (int pr = 0; pr < 4; ++pr) {
    const int kb = pr * 64;
    unsigned short* pb = pbase + (pr & 1) * 1056;  // 16 rows x 66 sh, double-buffered

    // packed V loads: contiguous 1KB per instruction
    bf16x8 vbr[2][4];
#pragma unroll
    for (int s2 = 0; s2 < 2; ++s2)
#pragma unroll
      for (int n = 0; n < 4; ++n)
        vbr[s2][n] = *(const bf16x8*)(Vw + (size_t)(((pr * 2 + s2) * 4) + n) * 512 + l * 8);

    // raw packed-bf16 P writes (both 32-key subchunks), zero VALU
#pragma unroll
    for (int s2 = 0; s2 < 2; ++s2) {
      const int wi = pr * 2 + s2;
      const u32x2 wv0 = {pkA[2 * wi],     pkB[2 * wi]};
      const u32x2 wv1 = {pkA[2 * wi + 1], pkB[2 * wi + 1]};
      *(u32x2*)(pb + lr * 66 + s2 * 32 + lg * 4) = wv0;
      *(u32x2*)(pb + lr * 66 + s2 * 32 + 16 + lg * 4) = wv1;
    }
    // coalesced attn stores: lane l -> row (l>>4)+4i, cols (l&15)*4..+3 (4x256B segs)
#pragma unroll
    for (int i = 0; i < 4; ++i) {
      const int row = (l >> 4) + i * 4;
      const us4 p4 = *(const us4*)(pb + row * 66 + (l & 15) * 4);
      const float rv = rv4[i];
      const f32x4 st = {__uint_as_float((unsigned)p4[0] << 16) * rv,
                        __uint_as_float((unsigned)p4[1] << 16) * rv,
                        __uint_as_float((unsigned)p4[2] << 16) * rv,
                        __uint_as_float((unsigned)p4[3] << 16) * rv};
      __builtin_nontemporal_store(st, (f32x4*)(attnB + (size_t)row * S_LEN + kb + (l & 15) * 4));
    }
    // PV on unnormalized P (rinv folded into epilogue)
#pragma unroll
    for (int s2 = 0; s2 < 2; ++s2) {
      const bf16x8 pa = *(const bf16x8*)(pb + lr * 66 + s2 * 32 + lg * 8);
#pragma unroll
      for (int n = 0; n < 4; ++n)
        oacc[n] = __builtin_amdgcn_mfma_f32_16x16x32_bf16(pa, vbr[s2][n], oacc[n], 0, 0, 0);
    }
  }

  // ---- cross-wave out reduction (unnormalized; rinv applied per q-row here) ----
  asm volatile("s_waitcnt lgkmcnt(0)" ::: "memory");
  float* outred = (float*)uni[w];
#pragma unroll
  for (int n = 0; n < 4; ++n)
#pragma unroll
    for (int jj = 0; jj < 4; ++jj)
      outred[(lg * 4 + jj) * 64 + n * 16 + lr] = oacc[n][jj];
  __syncthreads();
  if (threadIdx.x < 256) {
    const int q = threadIdx.x >> 4;
    const int d0 = (threadIdx.x & 15) * 4;
    const float rq = rinv16[q];
    float4 o = {0.f, 0.f, 0.f, 0.f};
#pragma unroll
    for (int ww = 0; ww < 8; ++ww) {
      const f32x4 sv = *(const f32x4*)((const float*)uni[ww] + q * 64 + d0);
      o.x += sv[0]; o.y += sv[1]; o.z += sv[2]; o.w += sv[3];
    }
    o.x *= rq; o.y *= rq; o.z *= rq; o.w *= rq;
    *(float4*)(outp + (size_t)(b * S_LEN + q0 + q) * DM + h * 64 + d0) = o;
  }
}

extern "C" void kernel_launch(void* const* d_in, const int* in_sizes, int n_in,
                              void* d_out, int out_size, void* d_ws, size_t ws_size,
                              hipStream_t stream) {
  const float* query = (const float*)d_in[0];
  const float* key_  = (const float*)d_in[1];
  const float* value = (const float*)d_in[2];
  const int*   mask  = (const int*)d_in[3];
  const float* Wq = (const float*)d_in[4];
  const float* bq = (const float*)d_in[5];
  const float* Wk = (const float*)d_in[6];
  const float* bk = (const float*)d_in[7];
  const float* Wv = (const float*)d_in[8];
  const float* bv = (const float*)d_in[9];

  float* outp  = (float*)d_out;
  float* attnp = outp + (size_t)2 * S_LEN * DM;

  unsigned short* ws  = (unsigned short*)d_ws;
  unsigned short* qbf = ws;
  unsigned short* kbf = qbf + 4194304;
  unsigned short* vbf = kbf + 4194304;
  unsigned short* wqb = vbf + 4194304;
  unsigned short* wkb = wqb + 1048576;
  unsigned short* wvb = wkb + 1048576;
  unsigned short* qp  = wvb + 1048576;
  unsigned short* kp  = qp + 4194304;
  unsigned short* vp  = kp + 4194304;
  unsigned short* vt  = vp + 4194304;
  unsigned int*   mb  = (unsigned int*)(vt + 4194304);   // 1 MB bitmask
  // packed K/V reuse qbf/kbf (dead after proj_gemm)
  unsigned short* kpk = qbf;
  unsigned short* vpk = kbf;

  cvt_kernel<<<4096, 256, 0, stream>>>(query, qbf, 1048576);
  cvt_kernel<<<4096, 256, 0, stream>>>(key_,  kbf, 1048576);
  cvt_kernel<<<4096, 256, 0, stream>>>(value, vbf, 1048576);
  cvt_kernel<<<1024, 256, 0, stream>>>(Wq, wqb, 262144);
  cvt_kernel<<<1024, 256, 0, stream>>>(Wk, wkb, 262144);
  cvt_kernel<<<1024, 256, 0, stream>>>(Wv, wvb, 262144);
  maskbits_kernel<<<1024, 256, 0, stream>>>(mask, mb);

  proj_gemm<<<dim3(8, 32, 3), 256, 0, stream>>>(qbf, wqb, bq, qp,
                                                kbf, wkb, bk, kp,
                                                vbf, wvb, bv, vp);
  transpose_bf<<<dim3(32, 128), 256, 0, stream>>>(vp, vt);
  kpack_kernel<<<2048, 256, 0, stream>>>(kp, kpk);
  vpack_kernel<<<2048, 256, 0, stream>>>(vt, vpk);
  attn15_kernel<<<4096, 512, 0, stream>>>(qp, kpk, vpk, mb, outp, attnp);
}

// Round 16
// 238.349 us; speedup vs baseline: 1.6196x; 1.0757x over previous
//
#include <hip/hip_runtime.h>
#include <hip/hip_bf16.h>
#include <cstdint>
#include <cstddef>

#define S_LEN 2048
#define DM 1024
#define NEGV -1.0e9f

typedef __attribute__((ext_vector_type(8))) short bf16x8;
typedef __attribute__((ext_vector_type(4))) float f32x4;
typedef __attribute__((ext_vector_type(4))) unsigned short us4;
typedef __attribute__((ext_vector_type(4))) int i32x4;
typedef __attribute__((ext_vector_type(4))) unsigned int ui32x4;
typedef __attribute__((ext_vector_type(2))) unsigned int u32x2;

__device__ __forceinline__ unsigned short f2bf(float f) {
  unsigned int u = __float_as_uint(f);
  unsigned int r = (u + 0x7fffu + ((u >> 16) & 1u)) >> 16;
  return (unsigned short)r;
}

__device__ __forceinline__ unsigned int pack_bf2(float a, float b) {
  return (unsigned int)f2bf(a) | ((unsigned int)f2bf(b) << 16);
}

__device__ __forceinline__ void async_copy16(const void* g, void* l) {
  __builtin_amdgcn_global_load_lds((const __attribute__((address_space(1))) void*)g,
                                   (__attribute__((address_space(3))) void*)l, 16, 0, 0);
}

// ---------------- merged f32 -> bf16 convert (all 6 tensors, one launch) ----------------
__global__ __launch_bounds__(256) void cvt_all(
    const float* __restrict__ q, const float* __restrict__ k, const float* __restrict__ v,
    const float* __restrict__ wq, const float* __restrict__ wk, const float* __restrict__ wv,
    unsigned short* __restrict__ qb, unsigned short* __restrict__ kb2, unsigned short* __restrict__ vb,
    unsigned short* __restrict__ wqb, unsigned short* __restrict__ wkb, unsigned short* __restrict__ wvb) {
  const int gid = blockIdx.x * 256 + threadIdx.x;   // 3*1048576 + 3*262144 = 3932160
  const float* src; unsigned short* dst; int idx;
  if (gid < 3145728) {
    const int j = gid >> 20; idx = gid & 1048575;
    src = (j == 0) ? q : (j == 1) ? k : v;
    dst = (j == 0) ? qb : (j == 1) ? kb2 : vb;
  } else {
    const int g = gid - 3145728;
    const int j = g >> 18; idx = g & 262143;
    src = (j == 0) ? wq : (j == 1) ? wk : wv;
    dst = (j == 0) ? wqb : (j == 1) ? wkb : wvb;
  }
  const float4 vv = reinterpret_cast<const float4*>(src)[idx];
  us4 o;
  o[0] = f2bf(vv.x); o[1] = f2bf(vv.y); o[2] = f2bf(vv.z); o[3] = f2bf(vv.w);
  reinterpret_cast<us4*>(dst)[idx] = o;
}

// ---------------- mask int32 -> bitmask (33.5 MB -> 1 MB) ----------------
__global__ __launch_bounds__(256) void maskbits_kernel(const int* __restrict__ mask,
                                                       unsigned int* __restrict__ mb) {
  const int idx = blockIdx.x * 256 + threadIdx.x;   // 262144 total
  const int row = idx >> 6, w = idx & 63;
  const int* src = mask + (size_t)row * S_LEN + w * 32;
  unsigned int r = 0;
#pragma unroll
  for (int j = 0; j < 8; ++j) {
    const i32x4 v = *(const i32x4*)(src + j * 4);
    r |= (v[0] ? 1u : 0u) << (j * 4 + 0);
    r |= (v[1] ? 1u : 0u) << (j * 4 + 1);
    r |= (v[2] ? 1u : 0u) << (j * 4 + 2);
    r |= (v[3] ? 1u : 0u) << (j * 4 + 3);
  }
  mb[(size_t)row * 64 + w] = r;
}

// ---------------- projection GEMM with XCD-supertiled grid ----------------
// 1-D grid 768: XCD c = bid&7 owns 12 (m,z) groups; within each, the 8 n-blocks
// sharing one A-tile run consecutively on the SAME XCD -> A re-reads are L2 hits
// (default (8,32,3) grid scattered them across 8 XCDs -> L3/HBM re-fetch).
__global__ __launch_bounds__(256) void proj_gemm(
    const unsigned short* __restrict__ Xq, const unsigned short* __restrict__ Wqw,
    const float* __restrict__ bq, unsigned short* __restrict__ Cq,
    const unsigned short* __restrict__ Xk, const unsigned short* __restrict__ Wkw,
    const float* __restrict__ bk, unsigned short* __restrict__ Ck,
    const unsigned short* __restrict__ Xv, const unsigned short* __restrict__ Wvw,
    const float* __restrict__ bv, unsigned short* __restrict__ Cv) {
  const int bid = blockIdx.x;
  const int c = bid & 7, s = bid >> 3;       // 96 blocks per XCD
  const int n0 = (s & 7) * 128;
  const int mzg = c * 12 + (s >> 3);         // 0..95 = (m,z) group
  const int m0 = (mzg & 31) * 128;
  const int z = mzg >> 5;

  const unsigned short* X; const unsigned short* W; const float* bias; unsigned short* C;
  if (z == 0)      { X = Xq; W = Wqw; bias = bq; C = Cq; }
  else if (z == 1) { X = Xk; W = Wkw; bias = bk; C = Ck; }
  else             { X = Xv; W = Wvw; bias = bv; C = Cv; }

  __shared__ unsigned short Ab[128 * 64];
  __shared__ unsigned short Bb[128 * 64];

  const int t  = threadIdx.x;
  const int wv2 = t >> 6, l = t & 63;
  const int lr = l & 15, lg = l >> 4;
  const int wr = wv2 >> 1, wc = wv2 & 1;

  const f32x4 fz = {0.f, 0.f, 0.f, 0.f};
  f32x4 acc[4][4];
#pragma unroll
  for (int m = 0; m < 4; ++m)
#pragma unroll
    for (int n = 0; n < 4; ++n) acc[m][n] = fz;

  const int srow = t >> 3;
  const int sc16 = t & 7;

  for (int kt = 0; kt < 16; ++kt) {
    const int kb = kt * 64;
#pragma unroll
    for (int it = 0; it < 4; ++it) {
      const int row = it * 32 + srow;
      const int c16 = sc16 ^ (row & 7);
      const unsigned short* gA = X + (size_t)(m0 + row) * DM + kb + c16 * 8;
      const unsigned short* gB = W + (size_t)(n0 + row) * DM + kb + c16 * 8;
      async_copy16(gA, (char*)Ab + it * 4096 + wv2 * 1024);
      async_copy16(gB, (char*)Bb + it * 4096 + wv2 * 1024);
    }
    __syncthreads();
#pragma unroll
    for (int kk = 0; kk < 2; ++kk) {
      bf16x8 af[4], bfr[4];
      const int c16 = kk * 4 + lg;
      const int sw = (c16 ^ (lr & 7)) * 16;
#pragma unroll
      for (int m = 0; m < 4; ++m) {
        const int row = wr * 64 + m * 16 + lr;
        af[m] = *(const bf16x8*)((const char*)Ab + row * 128 + sw);
      }
#pragma unroll
      for (int n = 0; n < 4; ++n) {
        const int row = wc * 64 + n * 16 + lr;
        bfr[n] = *(const bf16x8*)((const char*)Bb + row * 128 + sw);
      }
#pragma unroll
      for (int m = 0; m < 4; ++m)
#pragma unroll
        for (int n = 0; n < 4; ++n)
          acc[m][n] = __builtin_amdgcn_mfma_f32_16x16x32_bf16(af[m], bfr[n], acc[m][n], 0, 0, 0);
    }
    __syncthreads();
  }

#pragma unroll
  for (int n = 0; n < 4; ++n) {
    const int ccol = n0 + wc * 64 + n * 16 + lr;
    const float bb = bias[ccol];
#pragma unroll
    for (int m = 0; m < 4; ++m) {
      const int crow0 = m0 + wr * 64 + m * 16 + lg * 4;
#pragma unroll
      for (int j = 0; j < 4; ++j)
        C[(size_t)(crow0 + j) * DM + ccol] = f2bf(acc[m][n][j] + bb);
    }
  }
}

// ---------------- K repack into MFMA-fragment order ----------------
__global__ __launch_bounds__(256) void kpack_kernel(const unsigned short* __restrict__ Kp,
                                                    unsigned short* __restrict__ Kpack) {
  const int tid = blockIdx.x * 256 + threadIdx.x;   // 524288 total
  const int lane = tid & 63;
  const int chunk = (tid >> 6) & 1;
  const int kb = (tid >> 7) & 127;
  const int h = (tid >> 14) & 15;
  const int b = tid >> 18;
  const unsigned short* src = Kp + (size_t)(b * 2048 + kb * 16 + (lane & 15)) * 1024
                                 + h * 64 + chunk * 32 + (lane >> 4) * 8;
  unsigned short* dst = Kpack + ((size_t)((b * 16 + h) * 128 + kb) * 2 + chunk) * 512 + lane * 8;
  *(bf16x8*)dst = *(const bf16x8*)src;
}

// ---------------- fused V transpose + pack: vp [4096,1024] -> Vpack fragment order ----------------
// Replaces transpose_bf + vpack (one 32 MB round-trip + one launch saved).
// Block = one (b,h,w,pr) 64-key x 64-dim tile; LDS-staged; output 8 KB contiguous.
__global__ __launch_bounds__(256) void vtranspack_kernel(const unsigned short* __restrict__ Vp,
                                                         unsigned short* __restrict__ Vpack) {
  __shared__ unsigned short tile[64][72];   // +8 pad
  const int id = blockIdx.x;                // ((b*16+h)*8 + w)*4 + pr
  const int pr = id & 3;
  const int w  = (id >> 2) & 7;
  const int h  = (id >> 5) & 15;
  const int b  = id >> 9;
  const int t  = threadIdx.x;
  const int R0 = b * 2048 + w * 256 + pr * 64;
  const int C0 = h * 64;
  {
    const int row = t >> 2, q = t & 3;
    const unsigned short* src = Vp + (size_t)(R0 + row) * 1024 + C0 + q * 16;
    *(bf16x8*)&tile[row][q * 16] = *(const bf16x8*)src;
    *(bf16x8*)&tile[row][q * 16 + 8] = *(const bf16x8*)(src + 8);
  }
  __syncthreads();
  unsigned short* dstb = Vpack + ((size_t)(b * 16 + h) * 256 + (w * 4 + pr) * 8) * 512;
#pragma unroll
  for (int p2 = 0; p2 < 2; ++p2) {
    const int cid = p2 * 256 + t;
    const int blk = cid >> 6;               // s2*4 + n
    const int lane = cid & 63;
    const int s2 = blk >> 2, n = blk & 3;
    unsigned short v[8];
#pragma unroll
    for (int e = 0; e < 8; ++e)
      v[e] = tile[s2 * 32 + (lane >> 4) * 8 + e][n * 16 + (lane & 15)];
    *(bf16x8*)(dstb + (size_t)blk * 512 + lane * 8) = *(bf16x8*)v;
  }
}

// ---------------- fused attention (v15 structure, unchanged) ----------------
__global__ __launch_bounds__(512, 4) void attn16_kernel(
    const unsigned short* __restrict__ Qp, const unsigned short* __restrict__ Kpk,
    const unsigned short* __restrict__ Vpk, const unsigned int* __restrict__ mbits,
    float* __restrict__ outp, float* __restrict__ attnp) {
  __shared__ float rsred[8][16];
  __shared__ float rinv16[16];
  __shared__ char uni[8][4224];

  const int bx = blockIdx.x;
  const int c  = bx & 7;
  const int s  = bx >> 3;
  const int j  = s & 3;
  const int qt = s >> 2;
  const int bh = c * 4 + j;
  const int b  = bh >> 4, h = bh & 15;
  const int q0 = qt << 4;

  const int w = threadIdx.x >> 6, l = threadIdx.x & 63;
  const int lr = l & 15, lg = l >> 4;
  const int kw0 = w << 8;

  const float scale = 0.125f;
  const f32x4 fz = {0.f, 0.f, 0.f, 0.f};

  const unsigned short* Qh = Qp + (size_t)(b * S_LEN + q0 + lr) * DM + h * 64;
  const bf16x8 qf0 = *(const bf16x8*)(Qh + lg * 8);
  const bf16x8 qf1 = *(const bf16x8*)(Qh + 32 + lg * 8);

  const unsigned short* Kw = Kpk + (size_t)((b * 16 + h) * 128 + w * 16) * 1024;

  const unsigned int* mbr = mbits + ((size_t)(b * S_LEN + q0 + lr) << 6) + (kw0 >> 5);
  const ui32x4 mwa = *(const ui32x4*)(mbr);
  const ui32x4 mwb = *(const ui32x4*)(mbr + 4);

  unsigned int pkA[16], pkB[16];
  float rs = 0.f;
#pragma unroll
  for (int i = 0; i < 16; ++i) {
    const bf16x8 ka0 = *(const bf16x8*)(Kw + i * 1024 + l * 8);
    const bf16x8 ka1 = *(const bf16x8*)(Kw + i * 1024 + 512 + l * 8);
    f32x4 sc = fz;
    sc = __builtin_amdgcn_mfma_f32_16x16x32_bf16(ka0, qf0, sc, 0, 0, 0);
    sc = __builtin_amdgcn_mfma_f32_16x16x32_bf16(ka1, qf1, sc, 0, 0, 0);
    const unsigned int wsel = (i < 8) ? mwa[i >> 1] : mwb[(i - 8) >> 1];
    const unsigned int nib = (wsel >> ((i & 1) * 16 + lg * 4)) & 15u;
    const float e0 = __expf((nib & 1u) ? sc[0] * scale : NEGV);
    const float e1 = __expf((nib & 2u) ? sc[1] * scale : NEGV);
    const float e2 = __expf((nib & 4u) ? sc[2] * scale : NEGV);
    const float e3 = __expf((nib & 8u) ? sc[3] * scale : NEGV);
    rs += (e0 + e1) + (e2 + e3);
    pkA[i] = pack_bf2(e0, e1);
    pkB[i] = pack_bf2(e2, e3);
  }
  rs += __shfl_xor(rs, 16, 64);
  rs += __shfl_xor(rs, 32, 64);
  if (l < 16) rsred[w][l] = rs;
  __syncthreads();
  if (threadIdx.x < 16) {
    float s0 = 0.f;
#pragma unroll
    for (int ww = 0; ww < 8; ++ww) s0 += rsred[ww][threadIdx.x];
    rinv16[threadIdx.x] = 1.0f / s0;
  }
  __syncthreads();

  float rv4[4];
#pragma unroll
  for (int i = 0; i < 4; ++i) rv4[i] = rinv16[(l >> 4) + 4 * i];

  float* attnB = attnp + (size_t)((b * 16 + h) * S_LEN + q0) * S_LEN + kw0;
  const unsigned short* Vw = Vpk + ((size_t)(b * 16 + h) * 256 + w * 32) * 512;
  unsigned short* pbase = (unsigned short*)uni[w];

  f32x4 oacc[4];
#pragma unroll
  for (int n = 0; n < 4; ++n) oacc[n] = fz;

#pragma unroll
  for (int pr = 0; pr < 4; ++pr) {
    const int kb = pr * 64;
    unsigned short* pb = pbase + (pr & 1) * 1056;

    bf16x8 vbr[2][4];
#pragma unroll
    for (int s2 = 0; s2 < 2; ++s2)
#pragma unroll
      for (int n = 0; n < 4; ++n)
        vbr[s2][n] = *(const bf16x8*)(Vw + (size_t)(((pr * 2 + s2) * 4) + n) * 512 + l * 8);

#pragma unroll
    for (int s2 = 0; s2 < 2; ++s2) {
      const int wi = pr * 2 + s2;
      const u32x2 wv0 = {pkA[2 * wi],     pkB[2 * wi]};
      const u32x2 wv1 = {pkA[2 * wi + 1], pkB[2 * wi + 1]};
      *(u32x2*)(pb + lr * 66 + s2 * 32 + lg * 4) = wv0;
      *(u32x2*)(pb + lr * 66 + s2 * 32 + 16 + lg * 4) = wv1;
    }
#pragma unroll
    for (int i = 0; i < 4; ++i) {
      const int row = (l >> 4) + i * 4;
      const us4 p4 = *(const us4*)(pb + row * 66 + (l & 15) * 4);
      const float rv = rv4[i];
      const f32x4 st = {__uint_as_float((unsigned)p4[0] << 16) * rv,
                        __uint_as_float((unsigned)p4[1] << 16) * rv,
                        __uint_as_float((unsigned)p4[2] << 16) * rv,
                        __uint_as_float((unsigned)p4[3] << 16) * rv};
      __builtin_nontemporal_store(st, (f32x4*)(attnB + (size_t)row * S_LEN + kb + (l & 15) * 4));
    }
#pragma unroll
    for (int s2 = 0; s2 < 2; ++s2) {
      const bf16x8 pa = *(const bf16x8*)(pb + lr * 66 + s2 * 32 + lg * 8);
#pragma unroll
      for (int n = 0; n < 4; ++n)
        oacc[n] = __builtin_amdgcn_mfma_f32_16x16x32_bf16(pa, vbr[s2][n], oacc[n], 0, 0, 0);
    }
  }

  asm volatile("s_waitcnt lgkmcnt(0)" ::: "memory");
  float* outred = (float*)uni[w];
#pragma unroll
  for (int n = 0; n < 4; ++n)
#pragma unroll
    for (int jj = 0; jj < 4; ++jj)
      outred[(lg * 4 + jj) * 64 + n * 16 + lr] = oacc[n][jj];
  __syncthreads();
  if (threadIdx.x < 256) {
    const int q = threadIdx.x >> 4;
    const int d0 = (threadIdx.x & 15) * 4;
    const float rq = rinv16[q];
    float4 o = {0.f, 0.f, 0.f, 0.f};
#pragma unroll
    for (int ww = 0; ww < 8; ++ww) {
      const f32x4 sv = *(const f32x4*)((const float*)uni[ww] + q * 64 + d0);
      o.x += sv[0]; o.y += sv[1]; o.z += sv[2]; o.w += sv[3];
    }
    o.x *= rq; o.y *= rq; o.z *= rq; o.w *= rq;
    *(float4*)(outp + (size_t)(b * S_LEN + q0 + q) * DM + h * 64 + d0) = o;
  }
}

extern "C" void kernel_launch(void* const* d_in, const int* in_sizes, int n_in,
                              void* d_out, int out_size, void* d_ws, size_t ws_size,
                              hipStream_t stream) {
  const float* query = (const float*)d_in[0];
  const float* key_  = (const float*)d_in[1];
  const float* value = (const float*)d_in[2];
  const int*   mask  = (const int*)d_in[3];
  const float* Wq = (const float*)d_in[4];
  const float* bq = (const float*)d_in[5];
  const float* Wk = (const float*)d_in[6];
  const float* bk = (const float*)d_in[7];
  const float* Wv = (const float*)d_in[8];
  const float* bv = (const float*)d_in[9];

  float* outp  = (float*)d_out;
  float* attnp = outp + (size_t)2 * S_LEN * DM;

  unsigned short* ws  = (unsigned short*)d_ws;
  unsigned short* qbf = ws;
  unsigned short* kbf = qbf + 4194304;
  unsigned short* vbf = kbf + 4194304;
  unsigned short* wqb = vbf + 4194304;
  unsigned short* wkb = wqb + 1048576;
  unsigned short* wvb = wkb + 1048576;
  unsigned short* qp  = wvb + 1048576;
  unsigned short* kp  = qp + 4194304;
  unsigned short* vp  = kp + 4194304;
  unsigned int*   mb  = (unsigned int*)(vp + 4194304);   // 1 MB bitmask
  // packed K/V reuse qbf/kbf (dead after proj_gemm)
  unsigned short* kpk = qbf;
  unsigned short* vpk = kbf;

  cvt_all<<<15360, 256, 0, stream>>>(query, key_, value, Wq, Wk, Wv,
                                     qbf, kbf, vbf, wqb, wkb, wvb);
  maskbits_kernel<<<1024, 256, 0, stream>>>(mask, mb);

  proj_gemm<<<768, 256, 0, stream>>>(qbf, wqb, bq, qp,
                                     kbf, wkb, bk, kp,
                                     vbf, wvb, bv, vp);
  kpack_kernel<<<2048, 256, 0, stream>>>(kp, kpk);
  vtranspack_kernel<<<1024, 256, 0, stream>>>(vp, vpk);
  attn16_kernel<<<4096, 512, 0, stream>>>(qp, kpk, vpk, mb, outp, attnp);
}

// Round 17
// 230.196 us; speedup vs baseline: 1.6770x; 1.0354x over previous
//
#include <hip/hip_runtime.h>
#include <hip/hip_bf16.h>
#include <cstdint>
#include <cstddef>

#define S_LEN 2048
#define DM 1024
#define NEGV -1.0e9f

typedef __attribute__((ext_vector_type(8))) short bf16x8;
typedef __attribute__((ext_vector_type(4))) float f32x4;
typedef __attribute__((ext_vector_type(4))) unsigned short us4;
typedef __attribute__((ext_vector_type(4))) int i32x4;
typedef __attribute__((ext_vector_type(4))) unsigned int ui32x4;
typedef __attribute__((ext_vector_type(2))) unsigned int u32x2;

__device__ __forceinline__ unsigned short f2bf(float f) {
  unsigned int u = __float_as_uint(f);
  unsigned int r = (u + 0x7fffu + ((u >> 16) & 1u)) >> 16;
  return (unsigned short)r;
}

__device__ __forceinline__ unsigned int pack_bf2(float a, float b) {
  return (unsigned int)f2bf(a) | ((unsigned int)f2bf(b) << 16);
}

__device__ __forceinline__ void async_copy16(const void* g, void* l) {
  __builtin_amdgcn_global_load_lds((const __attribute__((address_space(1))) void*)g,
                                   (__attribute__((address_space(3))) void*)l, 16, 0, 0);
}

// ---------------- prep: f32->bf16 converts (6 tensors) + mask bitmask, one launch ----------------
__global__ __launch_bounds__(256) void prep_kernel(
    const float* __restrict__ q, const float* __restrict__ k, const float* __restrict__ v,
    const float* __restrict__ wq, const float* __restrict__ wk, const float* __restrict__ wv,
    const int* __restrict__ mask,
    unsigned short* __restrict__ qb, unsigned short* __restrict__ kb2, unsigned short* __restrict__ vb,
    unsigned short* __restrict__ wqb, unsigned short* __restrict__ wkb, unsigned short* __restrict__ wvb,
    unsigned int* __restrict__ mb) {
  if (blockIdx.x < 15360) {
    const int gid = blockIdx.x * 256 + threadIdx.x;   // 3*1048576 + 3*262144
    const float* src; unsigned short* dst; int idx;
    if (gid < 3145728) {
      const int j = gid >> 20; idx = gid & 1048575;
      src = (j == 0) ? q : (j == 1) ? k : v;
      dst = (j == 0) ? qb : (j == 1) ? kb2 : vb;
    } else {
      const int g = gid - 3145728;
      const int j = g >> 18; idx = g & 262143;
      src = (j == 0) ? wq : (j == 1) ? wk : wv;
      dst = (j == 0) ? wqb : (j == 1) ? wkb : wvb;
    }
    const float4 vv = reinterpret_cast<const float4*>(src)[idx];
    us4 o;
    o[0] = f2bf(vv.x); o[1] = f2bf(vv.y); o[2] = f2bf(vv.z); o[3] = f2bf(vv.w);
    reinterpret_cast<us4*>(dst)[idx] = o;
  } else {
    const int idx = (blockIdx.x - 15360) * 256 + threadIdx.x;  // 262144
    const int row = idx >> 6, w = idx & 63;
    const int* src = mask + (size_t)row * S_LEN + w * 32;
    unsigned int r = 0;
#pragma unroll
    for (int j = 0; j < 8; ++j) {
      const i32x4 vv = *(const i32x4*)(src + j * 4);
      r |= (vv[0] ? 1u : 0u) << (j * 4 + 0);
      r |= (vv[1] ? 1u : 0u) << (j * 4 + 1);
      r |= (vv[2] ? 1u : 0u) << (j * 4 + 2);
      r |= (vv[3] ? 1u : 0u) << (j * 4 + 3);
    }
    mb[(size_t)row * 64 + w] = r;
  }
}

// ---------------- projection GEMM, XCD-supertiled, PACKED epilogue ----------------
// Q written row-major; K and V written DIRECTLY in MFMA-fragment packed order
// (replaces kpack/vtranspack kernels: -32MB of round-trips, -2 launches).
// Epilogue stages the bf16 tile in LDS (reusing Ab/Bb), then each wave emits
// contiguous 1KB bursts in the packed order (lane = cid&63 -> lane*16B).
__global__ __launch_bounds__(256) void proj_gemm(
    const unsigned short* __restrict__ Xq, const unsigned short* __restrict__ Wqw,
    const float* __restrict__ bq, unsigned short* __restrict__ Cq,
    const unsigned short* __restrict__ Xk, const unsigned short* __restrict__ Wkw,
    const float* __restrict__ bk, unsigned short* __restrict__ Kpk,
    const unsigned short* __restrict__ Xv, const unsigned short* __restrict__ Wvw,
    const float* __restrict__ bv, unsigned short* __restrict__ Vpk) {
  __shared__ unsigned short smem[16640];   // Ab[8192] | Bb[8192] during loop; Ct[128*130] in epilogue
  unsigned short* Ab = smem;
  unsigned short* Bb = smem + 8192;

  const int bid = blockIdx.x;
  const int c = bid & 7, s = bid >> 3;     // 96 blocks per XCD
  const int n0 = (s & 7) * 128;
  const int mzg = c * 12 + (s >> 3);       // 0..95 = (m,z) group
  const int m0 = (mzg & 31) * 128;
  const int z = mzg >> 5;

  const unsigned short* X; const unsigned short* W; const float* bias;
  if (z == 0)      { X = Xq; W = Wqw; bias = bq; }
  else if (z == 1) { X = Xk; W = Wkw; bias = bk; }
  else             { X = Xv; W = Wvw; bias = bv; }

  const int t  = threadIdx.x;
  const int wv2 = t >> 6, l = t & 63;
  const int lr = l & 15, lg = l >> 4;
  const int wr = wv2 >> 1, wc = wv2 & 1;

  const f32x4 fz = {0.f, 0.f, 0.f, 0.f};
  f32x4 acc[4][4];
#pragma unroll
  for (int m = 0; m < 4; ++m)
#pragma unroll
    for (int n = 0; n < 4; ++n) acc[m][n] = fz;

  const int srow = t >> 3;
  const int sc16 = t & 7;

  for (int kt = 0; kt < 16; ++kt) {
    const int kb = kt * 64;
#pragma unroll
    for (int it = 0; it < 4; ++it) {
      const int row = it * 32 + srow;
      const int c16 = sc16 ^ (row & 7);
      const unsigned short* gA = X + (size_t)(m0 + row) * DM + kb + c16 * 8;
      const unsigned short* gB = W + (size_t)(n0 + row) * DM + kb + c16 * 8;
      async_copy16(gA, (char*)Ab + it * 4096 + wv2 * 1024);
      async_copy16(gB, (char*)Bb + it * 4096 + wv2 * 1024);
    }
    __syncthreads();
#pragma unroll
    for (int kk = 0; kk < 2; ++kk) {
      bf16x8 af[4], bfr[4];
      const int c16 = kk * 4 + lg;
      const int sw = (c16 ^ (lr & 7)) * 16;
#pragma unroll
      for (int m = 0; m < 4; ++m) {
        const int row = wr * 64 + m * 16 + lr;
        af[m] = *(const bf16x8*)((const char*)Ab + row * 128 + sw);
      }
#pragma unroll
      for (int n = 0; n < 4; ++n) {
        const int row = wc * 64 + n * 16 + lr;
        bfr[n] = *(const bf16x8*)((const char*)Bb + row * 128 + sw);
      }
#pragma unroll
      for (int m = 0; m < 4; ++m)
#pragma unroll
        for (int n = 0; n < 4; ++n)
          acc[m][n] = __builtin_amdgcn_mfma_f32_16x16x32_bf16(af[m], bfr[n], acc[m][n], 0, 0, 0);
    }
    __syncthreads();
  }

  // ---- epilogue: stage bf16 tile (+bias) in LDS, stride 130 ----
  unsigned short* Ct = smem;
#pragma unroll
  for (int n = 0; n < 4; ++n) {
    const int ccolL = wc * 64 + n * 16 + lr;
    const float bb = bias[n0 + ccolL];
#pragma unroll
    for (int m = 0; m < 4; ++m) {
      const int crowL = wr * 64 + m * 16 + lg * 4;
#pragma unroll
      for (int j = 0; j < 4; ++j)
        Ct[(crowL + j) * 130 + ccolL] = f2bf(acc[m][n][j] + bb);
    }
  }
  __syncthreads();

  if (z == 0) {
    // Q row-major: thread chunks of 8 shorts
#pragma unroll
    for (int i = 0; i < 8; ++i) {
      const int cid = i * 256 + t;
      const int row = cid >> 4, colc = cid & 15;
      const bf16x8 v8 = *(const bf16x8*)(Ct + row * 130 + colc * 8);
      *(bf16x8*)(Cq + (size_t)(m0 + row) * DM + n0 + colc * 8) = v8;
    }
  } else if (z == 1) {
    // K packed: Kpk[((b*16+h)*128+kb)*1024 + chunk*512 + lane*8]
    const int b = m0 >> 11;
    const int kbb = (m0 & 2047) >> 4;
    const int hb = n0 >> 6;
#pragma unroll
    for (int i = 0; i < 8; ++i) {
      const int cid = i * 256 + t;
      const int lane = cid & 63;
      const int sub = cid >> 6;            // 0..31
      const int chunk = sub & 1;
      const int hl = (sub >> 1) & 1;
      const int kbl = sub >> 2;            // 0..7
      const int row = kbl * 16 + (lane & 15);
      const int col = hl * 64 + chunk * 32 + (lane >> 4) * 8;
      const bf16x8 v8 = *(const bf16x8*)(Ct + row * 130 + col);
      unsigned short* dst = Kpk + ((size_t)((b * 16 + hb + hl) * 128 + kbb + kbl) * 2 + chunk) * 512 + lane * 8;
      *(bf16x8*)dst = v8;
    }
  } else {
    // V packed: Vpk[((b*16+h)*256+blk)*512 + lane*8], blk=((w*4+pr)*2+s2)*4+n
    const int b = m0 >> 11;
    const int k32b = (m0 & 2047) >> 5;
    const int hb = n0 >> 6;
#pragma unroll
    for (int i = 0; i < 8; ++i) {
      const int cid = i * 256 + t;
      const int lane = cid & 63;
      const int sub = cid >> 6;            // 0..31
      const int n = sub & 3;
      const int hl = (sub >> 2) & 1;
      const int l32 = sub >> 3;            // 0..3
      const int col = hl * 64 + n * 16 + (lane & 15);
      const int rbase = l32 * 32 + (lane >> 4) * 8;
      unsigned short v8[8];
#pragma unroll
      for (int e = 0; e < 8; ++e)
        v8[e] = Ct[(rbase + e) * 130 + col];
      const int k32 = k32b + l32;
      const int wv3 = k32 >> 3, pr = (k32 >> 1) & 3, s2 = k32 & 1;
      const int blk = ((wv3 * 4 + pr) * 2 + s2) * 4 + n;
      unsigned short* dst = Vpk + ((size_t)((b * 16 + hb + hl) * 256 + blk) * 512 + lane * 8);
      *(bf16x8*)dst = *(bf16x8*)v8;
    }
  }
}

// ---------------- fused attention (v15/v16 structure, unchanged) ----------------
__global__ __launch_bounds__(512, 4) void attn17_kernel(
    const unsigned short* __restrict__ Qp, const unsigned short* __restrict__ Kpk,
    const unsigned short* __restrict__ Vpk, const unsigned int* __restrict__ mbits,
    float* __restrict__ outp, float* __restrict__ attnp) {
  __shared__ float rsred[8][16];
  __shared__ float rinv16[16];
  __shared__ char uni[8][4224];

  const int bx = blockIdx.x;
  const int c  = bx & 7;
  const int s  = bx >> 3;
  const int j  = s & 3;
  const int qt = s >> 2;
  const int bh = c * 4 + j;
  const int b  = bh >> 4, h = bh & 15;
  const int q0 = qt << 4;

  const int w = threadIdx.x >> 6, l = threadIdx.x & 63;
  const int lr = l & 15, lg = l >> 4;
  const int kw0 = w << 8;

  const float scale = 0.125f;
  const f32x4 fz = {0.f, 0.f, 0.f, 0.f};

  const unsigned short* Qh = Qp + (size_t)(b * S_LEN + q0 + lr) * DM + h * 64;
  const bf16x8 qf0 = *(const bf16x8*)(Qh + lg * 8);
  const bf16x8 qf1 = *(const bf16x8*)(Qh + 32 + lg * 8);

  const unsigned short* Kw = Kpk + (size_t)((b * 16 + h) * 128 + w * 16) * 1024;

  const unsigned int* mbr = mbits + ((size_t)(b * S_LEN + q0 + lr) << 6) + (kw0 >> 5);
  const ui32x4 mwa = *(const ui32x4*)(mbr);
  const ui32x4 mwb = *(const ui32x4*)(mbr + 4);

  unsigned int pkA[16], pkB[16];
  float rs = 0.f;
#pragma unroll
  for (int i = 0; i < 16; ++i) {
    const bf16x8 ka0 = *(const bf16x8*)(Kw + i * 1024 + l * 8);
    const bf16x8 ka1 = *(const bf16x8*)(Kw + i * 1024 + 512 + l * 8);
    f32x4 sc = fz;
    sc = __builtin_amdgcn_mfma_f32_16x16x32_bf16(ka0, qf0, sc, 0, 0, 0);
    sc = __builtin_amdgcn_mfma_f32_16x16x32_bf16(ka1, qf1, sc, 0, 0, 0);
    const unsigned int wsel = (i < 8) ? mwa[i >> 1] : mwb[(i - 8) >> 1];
    const unsigned int nib = (wsel >> ((i & 1) * 16 + lg * 4)) & 15u;
    const float e0 = __expf((nib & 1u) ? sc[0] * scale : NEGV);
    const float e1 = __expf((nib & 2u) ? sc[1] * scale : NEGV);
    const float e2 = __expf((nib & 4u) ? sc[2] * scale : NEGV);
    const float e3 = __expf((nib & 8u) ? sc[3] * scale : NEGV);
    rs += (e0 + e1) + (e2 + e3);
    pkA[i] = pack_bf2(e0, e1);
    pkB[i] = pack_bf2(e2, e3);
  }
  rs += __shfl_xor(rs, 16, 64);
  rs += __shfl_xor(rs, 32, 64);
  if (l < 16) rsred[w][l] = rs;
  __syncthreads();
  if (threadIdx.x < 16) {
    float s0 = 0.f;
#pragma unroll
    for (int ww = 0; ww < 8; ++ww) s0 += rsred[ww][threadIdx.x];
    rinv16[threadIdx.x] = 1.0f / s0;
  }
  __syncthreads();

  float rv4[4];
#pragma unroll
  for (int i = 0; i < 4; ++i) rv4[i] = rinv16[(l >> 4) + 4 * i];

  float* attnB = attnp + (size_t)((b * 16 + h) * S_LEN + q0) * S_LEN + kw0;
  const unsigned short* Vw = Vpk + ((size_t)(b * 16 + h) * 256 + w * 32) * 512;
  unsigned short* pbase = (unsigned short*)uni[w];

  f32x4 oacc[4];
#pragma unroll
  for (int n = 0; n < 4; ++n) oacc[n] = fz;

#pragma unroll
  for (int pr = 0; pr < 4; ++pr) {
    const int kb = pr * 64;
    unsigned short* pb = pbase + (pr & 1) * 1056;

    bf16x8 vbr[2][4];
#pragma unroll
    for (int s2 = 0; s2 < 2; ++s2)
#pragma unroll
      for (int n = 0; n < 4; ++n)
        vbr[s2][n] = *(const bf16x8*)(Vw + (size_t)(((pr * 2 + s2) * 4) + n) * 512 + l * 8);

#pragma unroll
    for (int s2 = 0; s2 < 2; ++s2) {
      const int wi = pr * 2 + s2;
      const u32x2 wv0 = {pkA[2 * wi],     pkB[2 * wi]};
      const u32x2 wv1 = {pkA[2 * wi + 1], pkB[2 * wi + 1]};
      *(u32x2*)(pb + lr * 66 + s2 * 32 + lg * 4) = wv0;
      *(u32x2*)(pb + lr * 66 + s2 * 32 + 16 + lg * 4) = wv1;
    }
#pragma unroll
    for (int i = 0; i < 4; ++i) {
      const int row = (l >> 4) + i * 4;
      const us4 p4 = *(const us4*)(pb + row * 66 + (l & 15) * 4);
      const float rv = rv4[i];
      const f32x4 st = {__uint_as_float((unsigned)p4[0] << 16) * rv,
                        __uint_as_float((unsigned)p4[1] << 16) * rv,
                        __uint_as_float((unsigned)p4[2] << 16) * rv,
                        __uint_as_float((unsigned)p4[3] << 16) * rv};
      __builtin_nontemporal_store(st, (f32x4*)(attnB + (size_t)row * S_LEN + kb + (l & 15) * 4));
    }
#pragma unroll
    for (int s2 = 0; s2 < 2; ++s2) {
      const bf16x8 pa = *(const bf16x8*)(pb + lr * 66 + s2 * 32 + lg * 8);
#pragma unroll
      for (int n = 0; n < 4; ++n)
        oacc[n] = __builtin_amdgcn_mfma_f32_16x16x32_bf16(pa, vbr[s2][n], oacc[n], 0, 0, 0);
    }
  }

  asm volatile("s_waitcnt lgkmcnt(0)" ::: "memory");
  float* outred = (float*)uni[w];
#pragma unroll
  for (int n = 0; n < 4; ++n)
#pragma unroll
    for (int jj = 0; jj < 4; ++jj)
      outred[(lg * 4 + jj) * 64 + n * 16 + lr] = oacc[n][jj];
  __syncthreads();
  if (threadIdx.x < 256) {
    const int q = threadIdx.x >> 4;
    const int d0 = (threadIdx.x & 15) * 4;
    const float rq = rinv16[q];
    float4 o = {0.f, 0.f, 0.f, 0.f};
#pragma unroll
    for (int ww = 0; ww < 8; ++ww) {
      const f32x4 sv = *(const f32x4*)((const float*)uni[ww] + q * 64 + d0);
      o.x += sv[0]; o.y += sv[1]; o.z += sv[2]; o.w += sv[3];
    }
    o.x *= rq; o.y *= rq; o.z *= rq; o.w *= rq;
    *(float4*)(outp + (size_t)(b * S_LEN + q0 + q) * DM + h * 64 + d0) = o;
  }
}

extern "C" void kernel_launch(void* const* d_in, const int* in_sizes, int n_in,
                              void* d_out, int out_size, void* d_ws, size_t ws_size,
                              hipStream_t stream) {
  const float* query = (const float*)d_in[0];
  const float* key_  = (const float*)d_in[1];
  const float* value = (const float*)d_in[2];
  const int*   mask  = (const int*)d_in[3];
  const float* Wq = (const float*)d_in[4];
  const float* bq = (const float*)d_in[5];
  const float* Wk = (const float*)d_in[6];
  const float* bk = (const float*)d_in[7];
  const float* Wv = (const float*)d_in[8];
  const float* bv = (const float*)d_in[9];

  float* outp  = (float*)d_out;
  float* attnp = outp + (size_t)2 * S_LEN * DM;

  unsigned short* ws  = (unsigned short*)d_ws;
  unsigned short* qbf = ws;
  unsigned short* kbf = qbf + 4194304;
  unsigned short* vbf = kbf + 4194304;
  unsigned short* wqb = vbf + 4194304;
  unsigned short* wkb = wqb + 1048576;
  unsigned short* wvb = wkb + 1048576;
  unsigned short* qp  = wvb + 1048576;
  unsigned short* kpk = qp + 4194304;
  unsigned short* vpk = kpk + 4194304;
  unsigned int*   mb  = (unsigned int*)(vpk + 4194304);   // 1 MB bitmask

  prep_kernel<<<16384, 256, 0, stream>>>(query, key_, value, Wq, Wk, Wv, mask,
                                         qbf, kbf, vbf, wqb, wkb, wvb, mb);
  proj_gemm<<<768, 256, 0, stream>>>(qbf, wqb, bq, qp,
                                     kbf, wkb, bk, kpk,
                                     vbf, wvb, bv, vpk);
  attn17_kernel<<<4096, 512, 0, stream>>>(qp, kpk, vpk, mb, outp, attnp);
}

// Round 18
// 225.794 us; speedup vs baseline: 1.7097x; 1.0195x over previous
//
#include <hip/hip_runtime.h>
#include <hip/hip_bf16.h>
#include <cstdint>
#include <cstddef>

#define S_LEN 2048
#define DM 1024
#define NEGV -1.0e9f

typedef __attribute__((ext_vector_type(8))) short bf16x8;
typedef __attribute__((ext_vector_type(4))) float f32x4;
typedef __attribute__((ext_vector_type(4))) unsigned short us4;
typedef __attribute__((ext_vector_type(4))) int i32x4;
typedef __attribute__((ext_vector_type(4))) unsigned int ui32x4;
typedef __attribute__((ext_vector_type(2))) unsigned int u32x2;

__device__ __forceinline__ unsigned short f2bf(float f) {
  unsigned int u = __float_as_uint(f);
  unsigned int r = (u + 0x7fffu + ((u >> 16) & 1u)) >> 16;
  return (unsigned short)r;
}

__device__ __forceinline__ unsigned int pack_bf2(float a, float b) {
  return (unsigned int)f2bf(a) | ((unsigned int)f2bf(b) << 16);
}

__device__ __forceinline__ void async_copy16(const void* g, void* l) {
  __builtin_amdgcn_global_load_lds((const __attribute__((address_space(1))) void*)g,
                                   (__attribute__((address_space(3))) void*)l, 16, 0, 0);
}

// ---------------- prep: f32->bf16 converts (6 tensors) + mask bitmask, one launch ----------------
__global__ __launch_bounds__(256) void prep_kernel(
    const float* __restrict__ q, const float* __restrict__ k, const float* __restrict__ v,
    const float* __restrict__ wq, const float* __restrict__ wk, const float* __restrict__ wv,
    const int* __restrict__ mask,
    unsigned short* __restrict__ qb, unsigned short* __restrict__ kb2, unsigned short* __restrict__ vb,
    unsigned short* __restrict__ wqb, unsigned short* __restrict__ wkb, unsigned short* __restrict__ wvb,
    unsigned int* __restrict__ mb) {
  if (blockIdx.x < 15360) {
    const int gid = blockIdx.x * 256 + threadIdx.x;
    const float* src; unsigned short* dst; int idx;
    if (gid < 3145728) {
      const int j = gid >> 20; idx = gid & 1048575;
      src = (j == 0) ? q : (j == 1) ? k : v;
      dst = (j == 0) ? qb : (j == 1) ? kb2 : vb;
    } else {
      const int g = gid - 3145728;
      const int j = g >> 18; idx = g & 262143;
      src = (j == 0) ? wq : (j == 1) ? wk : wv;
      dst = (j == 0) ? wqb : (j == 1) ? wkb : wvb;
    }
    const float4 vv = reinterpret_cast<const float4*>(src)[idx];
    us4 o;
    o[0] = f2bf(vv.x); o[1] = f2bf(vv.y); o[2] = f2bf(vv.z); o[3] = f2bf(vv.w);
    reinterpret_cast<us4*>(dst)[idx] = o;
  } else {
    const int idx = (blockIdx.x - 15360) * 256 + threadIdx.x;
    const int row = idx >> 6, w = idx & 63;
    const int* src = mask + (size_t)row * S_LEN + w * 32;
    unsigned int r = 0;
#pragma unroll
    for (int j = 0; j < 8; ++j) {
      const i32x4 vv = *(const i32x4*)(src + j * 4);
      r |= (vv[0] ? 1u : 0u) << (j * 4 + 0);
      r |= (vv[1] ? 1u : 0u) << (j * 4 + 1);
      r |= (vv[2] ? 1u : 0u) << (j * 4 + 2);
      r |= (vv[3] ? 1u : 0u) << (j * 4 + 3);
    }
    mb[(size_t)row * 64 + w] = r;
  }
}

// ---------------- projection GEMM, XCD-supertiled, PACKED epilogue (v17, passed) ----------------
__global__ __launch_bounds__(256) void proj_gemm(
    const unsigned short* __restrict__ Xq, const unsigned short* __restrict__ Wqw,
    const float* __restrict__ bq, unsigned short* __restrict__ Cq,
    const unsigned short* __restrict__ Xk, const unsigned short* __restrict__ Wkw,
    const float* __restrict__ bk, unsigned short* __restrict__ Kpk,
    const unsigned short* __restrict__ Xv, const unsigned short* __restrict__ Wvw,
    const float* __restrict__ bv, unsigned short* __restrict__ Vpk) {
  __shared__ unsigned short smem[16640];
  unsigned short* Ab = smem;
  unsigned short* Bb = smem + 8192;

  const int bid = blockIdx.x;
  const int c = bid & 7, s = bid >> 3;
  const int n0 = (s & 7) * 128;
  const int mzg = c * 12 + (s >> 3);
  const int m0 = (mzg & 31) * 128;
  const int z = mzg >> 5;

  const unsigned short* X; const unsigned short* W; const float* bias;
  if (z == 0)      { X = Xq; W = Wqw; bias = bq; }
  else if (z == 1) { X = Xk; W = Wkw; bias = bk; }
  else             { X = Xv; W = Wvw; bias = bv; }

  const int t  = threadIdx.x;
  const int wv2 = t >> 6, l = t & 63;
  const int lr = l & 15, lg = l >> 4;
  const int wr = wv2 >> 1, wc = wv2 & 1;

  const f32x4 fz = {0.f, 0.f, 0.f, 0.f};
  f32x4 acc[4][4];
#pragma unroll
  for (int m = 0; m < 4; ++m)
#pragma unroll
    for (int n = 0; n < 4; ++n) acc[m][n] = fz;

  const int srow = t >> 3;
  const int sc16 = t & 7;

  for (int kt = 0; kt < 16; ++kt) {
    const int kb = kt * 64;
#pragma unroll
    for (int it = 0; it < 4; ++it) {
      const int row = it * 32 + srow;
      const int c16 = sc16 ^ (row & 7);
      const unsigned short* gA = X + (size_t)(m0 + row) * DM + kb + c16 * 8;
      const unsigned short* gB = W + (size_t)(n0 + row) * DM + kb + c16 * 8;
      async_copy16(gA, (char*)Ab + it * 4096 + wv2 * 1024);
      async_copy16(gB, (char*)Bb + it * 4096 + wv2 * 1024);
    }
    __syncthreads();
#pragma unroll
    for (int kk = 0; kk < 2; ++kk) {
      bf16x8 af[4], bfr[4];
      const int c16 = kk * 4 + lg;
      const int sw = (c16 ^ (lr & 7)) * 16;
#pragma unroll
      for (int m = 0; m < 4; ++m) {
        const int row = wr * 64 + m * 16 + lr;
        af[m] = *(const bf16x8*)((const char*)Ab + row * 128 + sw);
      }
#pragma unroll
      for (int n = 0; n < 4; ++n) {
        const int row = wc * 64 + n * 16 + lr;
        bfr[n] = *(const bf16x8*)((const char*)Bb + row * 128 + sw);
      }
#pragma unroll
      for (int m = 0; m < 4; ++m)
#pragma unroll
        for (int n = 0; n < 4; ++n)
          acc[m][n] = __builtin_amdgcn_mfma_f32_16x16x32_bf16(af[m], bfr[n], acc[m][n], 0, 0, 0);
    }
    __syncthreads();
  }

  unsigned short* Ct = smem;
#pragma unroll
  for (int n = 0; n < 4; ++n) {
    const int ccolL = wc * 64 + n * 16 + lr;
    const float bb = bias[n0 + ccolL];
#pragma unroll
    for (int m = 0; m < 4; ++m) {
      const int crowL = wr * 64 + m * 16 + lg * 4;
#pragma unroll
      for (int j = 0; j < 4; ++j)
        Ct[(crowL + j) * 130 + ccolL] = f2bf(acc[m][n][j] + bb);
    }
  }
  __syncthreads();

  if (z == 0) {
#pragma unroll
    for (int i = 0; i < 8; ++i) {
      const int cid = i * 256 + t;
      const int row = cid >> 4, colc = cid & 15;
      const bf16x8 v8 = *(const bf16x8*)(Ct + row * 130 + colc * 8);
      *(bf16x8*)(Cq + (size_t)(m0 + row) * DM + n0 + colc * 8) = v8;
    }
  } else if (z == 1) {
    const int b = m0 >> 11;
    const int kbb = (m0 & 2047) >> 4;
    const int hb = n0 >> 6;
#pragma unroll
    for (int i = 0; i < 8; ++i) {
      const int cid = i * 256 + t;
      const int lane = cid & 63;
      const int sub = cid >> 6;
      const int chunk = sub & 1;
      const int hl = (sub >> 1) & 1;
      const int kbl = sub >> 2;
      const int row = kbl * 16 + (lane & 15);
      const int col = hl * 64 + chunk * 32 + (lane >> 4) * 8;
      const bf16x8 v8 = *(const bf16x8*)(Ct + row * 130 + col);
      unsigned short* dst = Kpk + ((size_t)((b * 16 + hb + hl) * 128 + kbb + kbl) * 2 + chunk) * 512 + lane * 8;
      *(bf16x8*)dst = v8;
    }
  } else {
    const int b = m0 >> 11;
    const int k32b = (m0 & 2047) >> 5;
    const int hb = n0 >> 6;
#pragma unroll
    for (int i = 0; i < 8; ++i) {
      const int cid = i * 256 + t;
      const int lane = cid & 63;
      const int sub = cid >> 6;
      const int n = sub & 3;
      const int hl = (sub >> 2) & 1;
      const int l32 = sub >> 3;
      const int col = hl * 64 + n * 16 + (lane & 15);
      const int rbase = l32 * 32 + (lane >> 4) * 8;
      unsigned short v8[8];
#pragma unroll
      for (int e = 0; e < 8; ++e)
        v8[e] = Ct[(rbase + e) * 130 + col];
      const int k32 = k32b + l32;
      const int wv3 = k32 >> 3, pr = (k32 >> 1) & 3, s2 = k32 & 1;
      const int blk = ((wv3 * 4 + pr) * 2 + s2) * 4 + n;
      unsigned short* dst = Vpk + ((size_t)((b * 16 + hb + hl) * 256 + blk) * 512 + lane * 8);
      *(bf16x8*)dst = *(bf16x8*)v8;
    }
  }
}

// ---------------- fused attention v18: per-wave 512B-segment store phase ----------------
// vs v17: NT attn stores removed from the PV loop; after PV each wave runs 2
// half-phases: 8 u32x2 writes of raw packed P into its private [16][132] LDS slot
// (fits the 4224B uni slot exactly), lgkmcnt (wave-private, NO block barrier),
// then 8 NT store instrs each covering 2 rows x 512B contiguous (vs 4 rows x 256B).
// Isolates store-segment size cleanly (v13's 1KB test was confounded by 8 barriers).
__global__ __launch_bounds__(512, 4) void attn18_kernel(
    const unsigned short* __restrict__ Qp, const unsigned short* __restrict__ Kpk,
    const unsigned short* __restrict__ Vpk, const unsigned int* __restrict__ mbits,
    float* __restrict__ outp, float* __restrict__ attnp) {
  __shared__ float rsred[8][16];
  __shared__ float rinv16[16];
  __shared__ char uni[8][4224];

  const int bx = blockIdx.x;
  const int c  = bx & 7;
  const int s  = bx >> 3;
  const int j  = s & 3;
  const int qt = s >> 2;
  const int bh = c * 4 + j;
  const int b  = bh >> 4, h = bh & 15;
  const int q0 = qt << 4;

  const int w = threadIdx.x >> 6, l = threadIdx.x & 63;
  const int lr = l & 15, lg = l >> 4;
  const int kw0 = w << 8;

  const float scale = 0.125f;
  const f32x4 fz = {0.f, 0.f, 0.f, 0.f};

  const unsigned short* Qh = Qp + (size_t)(b * S_LEN + q0 + lr) * DM + h * 64;
  const bf16x8 qf0 = *(const bf16x8*)(Qh + lg * 8);
  const bf16x8 qf1 = *(const bf16x8*)(Qh + 32 + lg * 8);

  const unsigned short* Kw = Kpk + (size_t)((b * 16 + h) * 128 + w * 16) * 1024;

  const unsigned int* mbr = mbits + ((size_t)(b * S_LEN + q0 + lr) << 6) + (kw0 >> 5);
  const ui32x4 mwa = *(const ui32x4*)(mbr);
  const ui32x4 mwb = *(const ui32x4*)(mbr + 4);

  unsigned int pkA[16], pkB[16];
  float rs = 0.f;
#pragma unroll
  for (int i = 0; i < 16; ++i) {
    const bf16x8 ka0 = *(const bf16x8*)(Kw + i * 1024 + l * 8);
    const bf16x8 ka1 = *(const bf16x8*)(Kw + i * 1024 + 512 + l * 8);
    f32x4 sc = fz;
    sc = __builtin_amdgcn_mfma_f32_16x16x32_bf16(ka0, qf0, sc, 0, 0, 0);
    sc = __builtin_amdgcn_mfma_f32_16x16x32_bf16(ka1, qf1, sc, 0, 0, 0);
    const unsigned int wsel = (i < 8) ? mwa[i >> 1] : mwb[(i - 8) >> 1];
    const unsigned int nib = (wsel >> ((i & 1) * 16 + lg * 4)) & 15u;
    const float e0 = __expf((nib & 1u) ? sc[0] * scale : NEGV);
    const float e1 = __expf((nib & 2u) ? sc[1] * scale : NEGV);
    const float e2 = __expf((nib & 4u) ? sc[2] * scale : NEGV);
    const float e3 = __expf((nib & 8u) ? sc[3] * scale : NEGV);
    rs += (e0 + e1) + (e2 + e3);
    pkA[i] = pack_bf2(e0, e1);
    pkB[i] = pack_bf2(e2, e3);
  }
  rs += __shfl_xor(rs, 16, 64);
  rs += __shfl_xor(rs, 32, 64);
  if (l < 16) rsred[w][l] = rs;
  __syncthreads();
  if (threadIdx.x < 16) {
    float s0 = 0.f;
#pragma unroll
    for (int ww = 0; ww < 8; ++ww) s0 += rsred[ww][threadIdx.x];
    rinv16[threadIdx.x] = 1.0f / s0;
  }
  __syncthreads();

  const unsigned short* Vw = Vpk + ((size_t)(b * 16 + h) * 256 + w * 32) * 512;
  unsigned short* pbase = (unsigned short*)uni[w];

  f32x4 oacc[4];
#pragma unroll
  for (int n = 0; n < 4; ++n) oacc[n] = fz;

  // ---- PV loop: loads + LDS repack + MFMA only (stores moved out) ----
#pragma unroll
  for (int pr = 0; pr < 4; ++pr) {
    unsigned short* pb = pbase + (pr & 1) * 1056;

    bf16x8 vbr[2][4];
#pragma unroll
    for (int s2 = 0; s2 < 2; ++s2)
#pragma unroll
      for (int n = 0; n < 4; ++n)
        vbr[s2][n] = *(const bf16x8*)(Vw + (size_t)(((pr * 2 + s2) * 4) + n) * 512 + l * 8);

#pragma unroll
    for (int s2 = 0; s2 < 2; ++s2) {
      const int wi = pr * 2 + s2;
      const u32x2 wv0 = {pkA[2 * wi],     pkB[2 * wi]};
      const u32x2 wv1 = {pkA[2 * wi + 1], pkB[2 * wi + 1]};
      *(u32x2*)(pb + lr * 66 + s2 * 32 + lg * 4) = wv0;
      *(u32x2*)(pb + lr * 66 + s2 * 32 + 16 + lg * 4) = wv1;
    }
#pragma unroll
    for (int s2 = 0; s2 < 2; ++s2) {
      const bf16x8 pa = *(const bf16x8*)(pb + lr * 66 + s2 * 32 + lg * 8);
#pragma unroll
      for (int n = 0; n < 4; ++n)
        oacc[n] = __builtin_amdgcn_mfma_f32_16x16x32_bf16(pa, vbr[s2][n], oacc[n], 0, 0, 0);
    }
  }

  // ---- store phase: 2 halves, per-wave [16][132] transpose, 2x512B per instr ----
  asm volatile("s_waitcnt lgkmcnt(0)" ::: "memory");  // PV reads of pbase done
  float rv8[8];
#pragma unroll
  for (int jj = 0; jj < 8; ++jj) rv8[jj] = rinv16[(l >> 5) + 2 * jj];
  float* attnR = attnp + (size_t)((b * 16 + h) * S_LEN + q0) * S_LEN + kw0;
#pragma unroll
  for (int sh = 0; sh < 2; ++sh) {
#pragma unroll
    for (int i8 = 0; i8 < 8; ++i8) {
      const int i = sh * 8 + i8;
      const u32x2 wv = {pkA[i], pkB[i]};
      *(u32x2*)(pbase + lr * 132 + i8 * 16 + lg * 4) = wv;
    }
    asm volatile("s_waitcnt lgkmcnt(0)" ::: "memory");
#pragma unroll
    for (int jj = 0; jj < 8; ++jj) {
      const int row = (l >> 5) + 2 * jj;
      const us4 p4 = *(const us4*)(pbase + row * 132 + (l & 31) * 4);
      const float rv = rv8[jj];
      const f32x4 st = {__uint_as_float((unsigned)p4[0] << 16) * rv,
                        __uint_as_float((unsigned)p4[1] << 16) * rv,
                        __uint_as_float((unsigned)p4[2] << 16) * rv,
                        __uint_as_float((unsigned)p4[3] << 16) * rv};
      __builtin_nontemporal_store(st, (f32x4*)(attnR + (size_t)row * S_LEN + sh * 128 + (l & 31) * 4));
    }
    asm volatile("s_waitcnt lgkmcnt(0)" ::: "memory");  // reads drained before next-half writes
  }

  // ---- cross-wave out reduction ----
  float* outred = (float*)uni[w];
#pragma unroll
  for (int n = 0; n < 4; ++n)
#pragma unroll
    for (int jj = 0; jj < 4; ++jj)
      outred[(lg * 4 + jj) * 64 + n * 16 + lr] = oacc[n][jj];
  __syncthreads();
  if (threadIdx.x < 256) {
    const int q = threadIdx.x >> 4;
    const int d0 = (threadIdx.x & 15) * 4;
    const float rq = rinv16[q];
    float4 o = {0.f, 0.f, 0.f, 0.f};
#pragma unroll
    for (int ww = 0; ww < 8; ++ww) {
      const f32x4 sv = *(const f32x4*)((const float*)uni[ww] + q * 64 + d0);
      o.x += sv[0]; o.y += sv[1]; o.z += sv[2]; o.w += sv[3];
    }
    o.x *= rq; o.y *= rq; o.z *= rq; o.w *= rq;
    *(float4*)(outp + (size_t)(b * S_LEN + q0 + q) * DM + h * 64 + d0) = o;
  }
}

extern "C" void kernel_launch(void* const* d_in, const int* in_sizes, int n_in,
                              void* d_out, int out_size, void* d_ws, size_t ws_size,
                              hipStream_t stream) {
  const float* query = (const float*)d_in[0];
  const float* key_  = (const float*)d_in[1];
  const float* value = (const float*)d_in[2];
  const int*   mask  = (const int*)d_in[3];
  const float* Wq = (const float*)d_in[4];
  const float* bq = (const float*)d_in[5];
  const float* Wk = (const float*)d_in[6];
  const float* bk = (const float*)d_in[7];
  const float* Wv = (const float*)d_in[8];
  const float* bv = (const float*)d_in[9];

  float* outp  = (float*)d_out;
  float* attnp = outp + (size_t)2 * S_LEN * DM;

  unsigned short* ws  = (unsigned short*)d_ws;
  unsigned short* qbf = ws;
  unsigned short* kbf = qbf + 4194304;
  unsigned short* vbf = kbf + 4194304;
  unsigned short* wqb = vbf + 4194304;
  unsigned short* wkb = wqb + 1048576;
  unsigned short* wvb = wkb + 1048576;
  unsigned short* qp  = wvb + 1048576;
  unsigned short* kpk = qp + 4194304;
  unsigned short* vpk = kpk + 4194304;
  unsigned int*   mb  = (unsigned int*)(vpk + 4194304);

  prep_kernel<<<16384, 256, 0, stream>>>(query, key_, value, Wq, Wk, Wv, mask,
                                         qbf, kbf, vbf, wqb, wkb, wvb, mb);
  proj_gemm<<<768, 256, 0, stream>>>(qbf, wqb, bq, qp,
                                     kbf, wkb, bk, kpk,
                                     vbf, wvb, bv, vpk);
  attn18_kernel<<<4096, 512, 0, stream>>>(qp, kpk, vpk, mb, outp, attnp);
}